// Round 1
// baseline (2011.973 us; speedup 1.0000x reference)
//
#include <hip/hip_runtime.h>
#include <stdint.h>

#define DIM      2048
#define BATCH    16384
#define S_E      0.1f
#define S_C      0.1f
#define S_N      0.05f
#define DIVC     0.38f
#define NCAP     10.0f

typedef __attribute__((ext_vector_type(4))) float floatx4;
typedef __attribute__((ext_vector_type(8))) short short8;
typedef __attribute__((ext_vector_type(4))) short short4v;

__device__ __forceinline__ float bf2f(unsigned short u) {
  union { float f; unsigned v; } x; x.v = ((unsigned)u) << 16; return x.f;
}
__device__ __forceinline__ unsigned short f2bf(float f) {
  union { float f; unsigned v; } x; x.f = f;
  unsigned r = x.v + 0x7FFFu + ((x.v >> 16) & 1u);   // RNE
  return (unsigned short)(r >> 16);
}

__device__ __forceinline__ void gload_lds16(const void* g, void* l) {
  __builtin_amdgcn_global_load_lds((const __attribute__((address_space(1))) void*)g,
                                   (__attribute__((address_space(3))) void*)l,
                                   16, 0, 0);
}

// ---- dtype detector: flag=1 -> fp32 inputs, flag=0 -> bf16 ----
__global__ void k_detect(const unsigned short* __restrict__ h0u, int* __restrict__ flag) {
  const int lane = threadIdx.x;
  int bad = 0;
#pragma unroll
  for (int i = 0; i < 32; ++i) {
    const unsigned u = h0u[lane + i * 64];
    const unsigned e = (u >> 7) & 0xFF;
    bad |= (e >= 0x84);
  }
  const unsigned long long m = __ballot(bad);
  if (lane == 0) *flag = (m != 0ull) ? 1 : 0;
}

__global__ __launch_bounds__(256) void k_prep_w(
    const void* __restrict__ w1r, const void* __restrict__ w2r,
    const int* __restrict__ flag,
    unsigned short* __restrict__ W1b, unsigned short* __restrict__ W2b) {
  const void* src = blockIdx.y ? w2r : w1r;
  unsigned short* dst = blockIdx.y ? W2b : W1b;
  const long i4 = (long)blockIdx.x * 256 + threadIdx.x;
  if (*flag) {
    const float4 v = ((const float4*)src)[i4];
    short4v o;
    o.x = (short)f2bf(v.x); o.y = (short)f2bf(v.y);
    o.z = (short)f2bf(v.z); o.w = (short)f2bf(v.w);
    ((short4v*)dst)[i4] = o;
  } else {
    ((short4v*)dst)[i4] = ((const short4v*)src)[i4];
  }
}

__global__ __launch_bounds__(256) void k_prep_small(
    const void* __restrict__ b1r, const void* __restrict__ b2r,
    const void* __restrict__ a0r, const void* __restrict__ a1r,
    const void* __restrict__ a2r, const int* __restrict__ flag,
    float* __restrict__ b1f, float* __restrict__ b2f, float* __restrict__ dirs) {
  __shared__ float red[4];
  const int tid = threadIdx.x, wave = tid >> 6, lane = tid & 63;
  const int isf32 = *flag;
#pragma unroll
  for (int i = 0; i < 8; ++i) {
    const int idx = i * 256 + tid;
    b1f[idx] = isf32 ? ((const float*)b1r)[idx] : bf2f(((const unsigned short*)b1r)[idx]);
    b2f[idx] = isf32 ? ((const float*)b2r)[idx] : bf2f(((const unsigned short*)b2r)[idx]);
  }
  const void* ar[3] = { a0r, a1r, a2r };
  for (int a = 0; a < 3; ++a) {
    float v[8]; float s = 0.f;
#pragma unroll
    for (int i = 0; i < 8; ++i) {
      const int idx = i * 256 + tid;
      v[i] = isf32 ? ((const float*)ar[a])[idx] : bf2f(((const unsigned short*)ar[a])[idx]);
      s = fmaf(v[i], v[i], s);
    }
#pragma unroll
    for (int off = 32; off >= 1; off >>= 1) s += __shfl_xor(s, off);
    if (lane == 0) red[wave] = s;
    __syncthreads();
    const float S = red[0] + red[1] + red[2] + red[3];
    const float inv = 1.f / fmaxf(sqrtf(S), 1e-12f);
#pragma unroll
    for (int i = 0; i < 8; ++i) dirs[a * DIM + i * 256 + tid] = v[i] * inv;
    __syncthreads();
  }
}

// coefs from CAPPED row stats (unit dirs: ||h-d||^2 = S0 - 2 h.d + 1)
__device__ __forceinline__ float4 row_coef(float S0, float Se, float Sc, float Sn) {
  const float Li = 1.f / fmaxf(sqrtf(S0), 1e-12f);
  const float ce = S_E * (DIVC - Se * Li) / fmaxf(sqrtf(fmaxf(S0 - 2.f * Se + 1.f, 0.f)), 1e-12f);
  const float cc = S_C * (DIVC - Sc * Li) / fmaxf(sqrtf(fmaxf(S0 - 2.f * Sc + 1.f, 0.f)), 1e-12f);
  const float cn = S_N * (DIVC - Sn * Li) / fmaxf(sqrtf(fmaxf(S0 - 2.f * Sn + 1.f, 0.f)), 1e-12f);
  float4 c; c.x = 1.f - (ce + cc + cn); c.y = ce; c.z = cc; c.w = cn; return c;
}

// ---- boot: h0 -> hf (FULL) + hb + coef (s=1) + scl=1 ----
template<int FULL>
__global__ __launch_bounds__(256) void k_boot(
    const void* __restrict__ h0raw, const int* __restrict__ flag,
    const float* __restrict__ dirs, float* __restrict__ hf,
    unsigned short* __restrict__ hb, float4* __restrict__ coef,
    float* __restrict__ scl) {
  __shared__ float red[16];
  const long row = blockIdx.x;
  const int tid = threadIdx.x, wave = tid >> 6, lane = tid & 63;
  const int isf32 = *flag;
  float h[8];
  float s0 = 0.f, se = 0.f, sc = 0.f, sn = 0.f;
#pragma unroll
  for (int i = 0; i < 2; ++i) {
    const int c4 = i * 256 + tid;
    float4 hv;
    if (isf32) {
      hv = ((const float4*)h0raw + row * (DIM/4))[c4];
    } else {
      const short4v hs = ((const short4v*)h0raw + row * (DIM/4))[c4];
      hv.x = bf2f((unsigned short)hs.x); hv.y = bf2f((unsigned short)hs.y);
      hv.z = bf2f((unsigned short)hs.z); hv.w = bf2f((unsigned short)hs.w);
    }
    const float4 ev = ((const float4*)dirs)[c4];
    const float4 cv = ((const float4*)(dirs + DIM))[c4];
    const float4 nv = ((const float4*)(dirs + 2*DIM))[c4];
    h[i*4+0]=hv.x; h[i*4+1]=hv.y; h[i*4+2]=hv.z; h[i*4+3]=hv.w;
    s0 = fmaf(hv.x,hv.x,fmaf(hv.y,hv.y,fmaf(hv.z,hv.z,fmaf(hv.w,hv.w,s0))));
    se = fmaf(hv.x,ev.x,fmaf(hv.y,ev.y,fmaf(hv.z,ev.z,fmaf(hv.w,ev.w,se))));
    sc = fmaf(hv.x,cv.x,fmaf(hv.y,cv.y,fmaf(hv.z,cv.z,fmaf(hv.w,cv.w,sc))));
    sn = fmaf(hv.x,nv.x,fmaf(hv.y,nv.y,fmaf(hv.z,nv.z,fmaf(hv.w,nv.w,sn))));
  }
#pragma unroll
  for (int off = 32; off >= 1; off >>= 1) {
    s0 += __shfl_xor(s0, off); se += __shfl_xor(se, off);
    sc += __shfl_xor(sc, off); sn += __shfl_xor(sn, off);
  }
  if (lane == 0) { red[wave*4+0]=s0; red[wave*4+1]=se; red[wave*4+2]=sc; red[wave*4+3]=sn; }
  __syncthreads();
  if (tid == 0) {
    const float S0 = red[0]+red[4]+red[8]+red[12];
    const float Se = red[1]+red[5]+red[9]+red[13];
    const float Sc = red[2]+red[6]+red[10]+red[14];
    const float Sn = red[3]+red[7]+red[11]+red[15];
    coef[row] = row_coef(S0, Se, Sc, Sn);   // h0 is not pre-capped; s=1
    scl[row] = 1.f;
  }
#pragma unroll
  for (int i = 0; i < 2; ++i) {
    const int c4 = i * 256 + tid;
    if (FULL) {
      float4 o; o.x=h[i*4+0]; o.y=h[i*4+1]; o.z=h[i*4+2]; o.w=h[i*4+3];
      ((float4*)hf + row * (DIM/4))[c4] = o;
    }
    short4v ob;
    ob.x=(short)f2bf(h[i*4+0]); ob.y=(short)f2bf(h[i*4+1]);
    ob.z=(short)f2bf(h[i*4+2]); ob.w=(short)f2bf(h[i*4+3]);
    ((short4v*)hb + row * (DIM/4))[c4] = ob;
  }
}

// ============================================================================
// 256x256-tile deep-pipeline GEMM core (BK=32, 4-slot LDS ring, counted vmcnt)
//
// - 512 threads = 8 waves (2 M x 4 N); each wave owns a 128x64 C-subtile.
// - LDS: 4 slots x (A 16KB + B 16KB) = 128 KB.  Slot s holds K-tile t (t&3==s)
//   as [256][32] bf16 row-major (64B rows).  At BK=32 the b128 fragment reads
//   are naturally at the LDS minimum (8 lanes / 4-bank group) -> no swizzle.
// - Pipeline: tile t's phases stage tile t+3 into slot (t+3)&3 == (t-1)&3,
//   whose reads completed before the previous boundary barrier -> race-free.
// - Boundary wait: s_waitcnt vmcnt(8) (tiles t+2,t+3 = 8 loads in flight),
//   raw s_barrier (NO implicit vmcnt(0) drain, unlike __syncthreads).
// - 2 phases / K-tile, 16 MFMA each, s_setprio(1) around the MFMA cluster.
// ============================================================================

template<int VM, bool STG>
__device__ __forceinline__ void gemm_tile(
    const int t, const unsigned short* __restrict__ Ag,
    const unsigned short* __restrict__ Bg, char* __restrict__ smem,
    const int tid, const int wm, const int wn, const int l16, const int quad,
    floatx4 (&acc)[8][4], short8 (&bfr)[4]) {
  const short* As = (const short*)(smem + (t & 3) * 32768) + (wm + l16) * 32 + quad * 8;
  const short* Bs = (const short*)(smem + (t & 3) * 32768 + 16384) + (wn + l16) * 32 + quad * 8;
  // ---- phase A: read B-frags + A-frags 0..3, stage A(t+3), MFMA upper half ----
  short8 af[4];
#pragma unroll
  for (int j = 0; j < 4; ++j) bfr[j] = *(const short8*)(Bs + j * 512);
#pragma unroll
  for (int i = 0; i < 4; ++i) af[i] = *(const short8*)(As + i * 512);
  if (STG) {
    const unsigned short* as = Ag + (t + 3) * 32;
    char* dA = smem + ((t + 3) & 3) * 32768 + tid * 16;
    gload_lds16(as, dA);
    gload_lds16(as + (size_t)128 * DIM, dA + 8192);
  }
  __builtin_amdgcn_s_barrier();
  __builtin_amdgcn_sched_barrier(0);
  __builtin_amdgcn_s_setprio(1);
#pragma unroll
  for (int i = 0; i < 4; ++i)
#pragma unroll
    for (int j = 0; j < 4; ++j)
      acc[i][j] = __builtin_amdgcn_mfma_f32_16x16x32_bf16(af[i], bfr[j], acc[i][j], 0, 0, 0);
  __builtin_amdgcn_s_setprio(0);
  __builtin_amdgcn_s_barrier();
  __builtin_amdgcn_sched_barrier(0);
  // ---- phase B: read A-frags 4..7, stage B(t+3), MFMA lower half ----
#pragma unroll
  for (int i = 0; i < 4; ++i) af[i] = *(const short8*)(As + (4 + i) * 512);
  if (STG) {
    const unsigned short* bs = Bg + (t + 3) * 32;
    char* dB = smem + ((t + 3) & 3) * 32768 + 16384 + tid * 16;
    gload_lds16(bs, dB);
    gload_lds16(bs + (size_t)128 * DIM, dB + 8192);
  }
  __builtin_amdgcn_s_barrier();
  __builtin_amdgcn_sched_barrier(0);
  __builtin_amdgcn_s_setprio(1);
#pragma unroll
  for (int i = 0; i < 4; ++i)
#pragma unroll
    for (int j = 0; j < 4; ++j)
      acc[4 + i][j] = __builtin_amdgcn_mfma_f32_16x16x32_bf16(af[i], bfr[j], acc[4 + i][j], 0, 0, 0);
  __builtin_amdgcn_s_setprio(0);
  __builtin_amdgcn_sched_barrier(0);
  // ---- K-tile boundary: counted wait (tile t+1 landed), never drain mid-loop
  if constexpr (VM == 8)      asm volatile("s_waitcnt vmcnt(8)" ::: "memory");
  else if constexpr (VM == 4) asm volatile("s_waitcnt vmcnt(4)" ::: "memory");
  else if constexpr (VM == 0) asm volatile("s_waitcnt vmcnt(0)" ::: "memory");
  __builtin_amdgcn_s_barrier();
  __builtin_amdgcn_sched_barrier(0);
}

__device__ __forceinline__ void gemm_main(
    const unsigned short* __restrict__ A, const unsigned short* __restrict__ B,
    char* __restrict__ smem, const int tid, const int wm, const int wn,
    const int l16, const int quad, const long m0, const long n0,
    floatx4 (&acc)[8][4]) {
  // stage addressing: chunk c = j*512+tid -> row = j*128 + tid/4, colchunk = tid&3
  const unsigned short* Ag = A + (m0 + (tid >> 2)) * DIM + (tid & 3) * 8;
  const unsigned short* Bg = B + (n0 + (tid >> 2)) * DIM + (tid & 3) * 8;
  // prologue: stage tiles 0,1,2 (12 loads/wave)
#pragma unroll
  for (int tt = 0; tt < 3; ++tt) {
    const unsigned short* as = Ag + tt * 32;
    const unsigned short* bs = Bg + tt * 32;
    char* dA = smem + tt * 32768 + tid * 16;
    char* dB = dA + 16384;
    gload_lds16(as, dA);
    gload_lds16(as + (size_t)128 * DIM, dA + 8192);
    gload_lds16(bs, dB);
    gload_lds16(bs + (size_t)128 * DIM, dB + 8192);
  }
  asm volatile("s_waitcnt vmcnt(8)" ::: "memory");   // tile 0 landed; 1,2 in flight
  __builtin_amdgcn_s_barrier();
  __builtin_amdgcn_sched_barrier(0);
  short8 bfr[4];
#pragma unroll 1
  for (int t = 0; t < DIM / 32 - 3; ++t)
    gemm_tile<8, true >(t, Ag, Bg, smem, tid, wm, wn, l16, quad, acc, bfr);
  gemm_tile<4, false>(DIM / 32 - 3, Ag, Bg, smem, tid, wm, wn, l16, quad, acc, bfr);
  gemm_tile<0, false>(DIM / 32 - 2, Ag, Bg, smem, tid, wm, wn, l16, quad, acc, bfr);
  gemm_tile<-1, false>(DIM / 32 - 1, Ag, Bg, smem, tid, wm, wn, l16, quad, acc, bfr);
}

// ---- GEMM1: T = tanh(scl[row]*(hb @ W1^T) + b1) ----
__global__ __launch_bounds__(512, 2) void gemm_tanh(
    const unsigned short* __restrict__ A, const unsigned short* __restrict__ B,
    const float* __restrict__ bias, const float* __restrict__ scl,
    unsigned short* __restrict__ Cb) {
  __shared__ __align__(16) char smem[131072];
  const int tid = threadIdx.x, wave = tid >> 6, lane = tid & 63;
  const int quad = lane >> 4, l16 = lane & 15;
  const int wm = (wave >> 2) * 128, wn = (wave & 3) * 64;
  const long m0 = (long)blockIdx.y * 256, n0 = (long)blockIdx.x * 256;
  floatx4 acc[8][4] = {};
  gemm_main(A, B, smem, tid, wm, wn, l16, quad, m0, n0, acc);
  __syncthreads();
  asm volatile("" ::: "memory");
  // epilogue: scale rows, bias, tanh -> bf16 into LDS, then coalesced stores
  short* Eh = (short*)smem;           // [256][256] bf16 = 128KB
  float sr[32];
#pragma unroll
  for (int i = 0; i < 8; ++i) {
    const float4 s4 = *(const float4*)(scl + m0 + wm + i * 16 + quad * 4);
    sr[i*4+0] = s4.x; sr[i*4+1] = s4.y; sr[i*4+2] = s4.z; sr[i*4+3] = s4.w;
  }
  float bcol[4];
#pragma unroll
  for (int j = 0; j < 4; ++j) bcol[j] = bias[n0 + wn + j * 16 + l16];
#pragma unroll
  for (int i = 0; i < 8; ++i) {
    const int row = wm + i * 16 + quad * 4;
#pragma unroll
    for (int j = 0; j < 4; ++j) {
      const int col = wn + j * 16 + l16;
#pragma unroll
      for (int r = 0; r < 4; ++r) {
        const float x = fmaf(sr[i*4+r], acc[i][j][r], bcol[j]);
        const float tt = 1.f - 2.f / (__expf(2.f * x) + 1.f);
        Eh[(row + r) * 256 + col] = (short)f2bf(tt);
      }
    }
  }
  __syncthreads();
#pragma unroll
  for (int s = 0; s < 16; ++s) {
    const int g = s * 512 + tid;
    const int row = g >> 5, c8 = (g & 31) * 8;
    *(short8*)(Cb + (m0 + row) * DIM + n0 + c8) = *(const short8*)(Eh + row * 256 + c8);
  }
}

// ---- GEMM2 + fused collapse update (uncapped h master; cf.x = ch*s folded) ----
template<int FULL>
__global__ __launch_bounds__(512, 2) void gemm_update(
    const unsigned short* __restrict__ A, const unsigned short* __restrict__ B,
    const float* __restrict__ bias, float* __restrict__ hf,
    unsigned short* __restrict__ hb, const float4* __restrict__ coef,
    const float* __restrict__ dirs) {
  __shared__ __align__(16) char smem[131072];
  const int tid = threadIdx.x, wave = tid >> 6, lane = tid & 63;
  const int quad = lane >> 4, l16 = lane & 15;
  const int wm = (wave >> 2) * 128, wn = (wave & 3) * 64;
  const long m0 = (long)blockIdx.y * 256, n0 = (long)blockIdx.x * 256;
  floatx4 acc[8][4] = {};
  gemm_main(A, B, smem, tid, wm, wn, l16, quad, m0, n0, acc);
  asm volatile("" ::: "memory");
  // two j-half passes through LDS (fp32); coalesced float4 RMW of hf + hb mirror
  float* Ef = (float*)smem;           // [256][128] fp32 = 128KB
#pragma unroll
  for (int p = 0; p < 2; ++p) {
    __syncthreads();
#pragma unroll
    for (int i = 0; i < 8; ++i) {
      const int row = wm + i * 16 + quad * 4;
#pragma unroll
      for (int jj = 0; jj < 2; ++jj) {
        const int cc = (wn >> 1) + jj * 16 + l16;       // wave's 32-col stripe pair
#pragma unroll
        for (int r = 0; r < 4; ++r)
          Ef[(row + r) * 128 + cc] = acc[i][p * 2 + jj][r];
      }
    }
    __syncthreads();
#pragma unroll
    for (int s = 0; s < 16; ++s) {
      const int q = s * 512 + tid;
      const int row = q >> 5, c4 = (q & 31) * 4;
      const int col = ((c4 >> 5) * 64) + p * 32 + (c4 & 31);  // de-compact 32-stripes
      const long gr = m0 + row, gc = n0 + col;
      const float4 e  = *(const float4*)(Ef + row * 128 + c4);
      const float4 bv = *(const float4*)(bias + gc);
      const float4 de = *(const float4*)(dirs + gc);
      const float4 dc = *(const float4*)(dirs + DIM + gc);
      const float4 dn = *(const float4*)(dirs + 2*DIM + gc);
      const float4 cf = coef[gr];
      float4 hv;
      if (FULL) {
        hv = *(const float4*)(hf + gr * DIM + gc);
      } else {
        const short4v hs = *(const short4v*)(hb + gr * DIM + gc);
        hv.x = bf2f((unsigned short)hs.x); hv.y = bf2f((unsigned short)hs.y);
        hv.z = bf2f((unsigned short)hs.z); hv.w = bf2f((unsigned short)hs.w);
      }
      float4 v;
      v.x = e.x + bv.x; v.y = e.y + bv.y; v.z = e.z + bv.z; v.w = e.w + bv.w;
      v.x = fmaf(cf.x, hv.x, v.x); v.y = fmaf(cf.x, hv.y, v.y);
      v.z = fmaf(cf.x, hv.z, v.z); v.w = fmaf(cf.x, hv.w, v.w);
      v.x = fmaf(cf.y, de.x, v.x); v.y = fmaf(cf.y, de.y, v.y);
      v.z = fmaf(cf.y, de.z, v.z); v.w = fmaf(cf.y, de.w, v.w);
      v.x = fmaf(cf.z, dc.x, v.x); v.y = fmaf(cf.z, dc.y, v.y);
      v.z = fmaf(cf.z, dc.z, v.z); v.w = fmaf(cf.z, dc.w, v.w);
      v.x = fmaf(cf.w, dn.x, v.x); v.y = fmaf(cf.w, dn.y, v.y);
      v.z = fmaf(cf.w, dn.z, v.z); v.w = fmaf(cf.w, dn.w, v.w);
      if (FULL) *(float4*)(hf + gr * DIM + gc) = v;
      short4v ob;
      ob.x = (short)f2bf(v.x); ob.y = (short)f2bf(v.y);
      ob.z = (short)f2bf(v.z); ob.w = (short)f2bf(v.w);
      *(short4v*)(hb + gr * DIM + gc) = ob;
    }
  }
}

// ---- stats: read hb (uncapped), emit next-layer coef (cf.x=ch*s) + scl=s ----
__global__ __launch_bounds__(256) void k_stats(
    const unsigned short* __restrict__ hb, const float* __restrict__ dirs,
    float4* __restrict__ coef, float* __restrict__ scl) {
  const int tid = threadIdx.x, w = tid >> 6, lane = tid & 63;
  const long row = (long)blockIdx.x * 4 + w;
  const unsigned short* hr = hb + row * DIM;
  float s0 = 0.f, se = 0.f, sc = 0.f, sn = 0.f;
#pragma unroll
  for (int i = 0; i < 4; ++i) {
    const int o = i * 512 + lane * 8;
    const short8 h8 = *(const short8*)(hr + o);
    float h[8];
#pragma unroll
    for (int q = 0; q < 8; ++q) h[q] = bf2f((unsigned short)h8[q]);
    const float4 e0 = *(const float4*)(dirs + o),       e1 = *(const float4*)(dirs + o + 4);
    const float4 c0 = *(const float4*)(dirs + DIM + o), c1 = *(const float4*)(dirs + DIM + o + 4);
    const float4 n0v = *(const float4*)(dirs + 2*DIM + o), n1 = *(const float4*)(dirs + 2*DIM + o + 4);
    const float ee[8] = { e0.x,e0.y,e0.z,e0.w, e1.x,e1.y,e1.z,e1.w };
    const float ccv[8] = { c0.x,c0.y,c0.z,c0.w, c1.x,c1.y,c1.z,c1.w };
    const float nn[8] = { n0v.x,n0v.y,n0v.z,n0v.w, n1.x,n1.y,n1.z,n1.w };
#pragma unroll
    for (int q = 0; q < 8; ++q) {
      s0 = fmaf(h[q], h[q], s0);
      se = fmaf(h[q], ee[q], se);
      sc = fmaf(h[q], ccv[q], sc);
      sn = fmaf(h[q], nn[q], sn);
    }
  }
#pragma unroll
  for (int off = 32; off >= 1; off >>= 1) {
    s0 += __shfl_xor(s0, off); se += __shfl_xor(se, off);
    sc += __shfl_xor(sc, off); sn += __shfl_xor(sn, off);
  }
  if (lane == 0) {
    const float nrm = sqrtf(s0);
    const float s = (nrm > NCAP) ? (NCAP / (nrm + 1e-8f)) : 1.f;
    float4 cf = row_coef(s0 * s * s, se * s, sc * s, sn * s);
    cf.x *= s;                       // applied to UNCAPPED h master
    coef[row] = cf;
    scl[row] = s;
  }
}

// ---- finish: norm-cap final h_pre, write d_out (dtype by flag) ----
template<int FULL>
__global__ __launch_bounds__(256) void k_finish(
    const float* __restrict__ hf, const unsigned short* __restrict__ hb,
    const int* __restrict__ flag, void* __restrict__ dout) {
  const int tid = threadIdx.x, w = tid >> 6, lane = tid & 63;
  const long row = (long)blockIdx.x * 4 + w;
  float4 hv[8];
  float s0 = 0.f;
#pragma unroll
  for (int i = 0; i < 8; ++i) {
    const int o = i * 256 + lane * 4;
    if (FULL) {
      hv[i] = *(const float4*)(hf + row * DIM + o);
    } else {
      const short4v hs = *(const short4v*)(hb + row * DIM + o);
      hv[i].x = bf2f((unsigned short)hs.x); hv[i].y = bf2f((unsigned short)hs.y);
      hv[i].z = bf2f((unsigned short)hs.z); hv[i].w = bf2f((unsigned short)hs.w);
    }
    s0 = fmaf(hv[i].x,hv[i].x,fmaf(hv[i].y,hv[i].y,fmaf(hv[i].z,hv[i].z,fmaf(hv[i].w,hv[i].w,s0))));
  }
#pragma unroll
  for (int off = 32; off >= 1; off >>= 1) s0 += __shfl_xor(s0, off);
  const float nrm = sqrtf(s0);
  const float s = (nrm > NCAP) ? (NCAP / (nrm + 1e-8f)) : 1.f;
  const int isf32 = *flag;
#pragma unroll
  for (int i = 0; i < 8; ++i) {
    const int o = i * 256 + lane * 4;
    float4 v;
    v.x = hv[i].x * s; v.y = hv[i].y * s; v.z = hv[i].z * s; v.w = hv[i].w * s;
    if (isf32) {
      *((float4*)dout + (row * DIM + o) / 4) = v;
    } else {
      short4v ob;
      ob.x = (short)f2bf(v.x); ob.y = (short)f2bf(v.y);
      ob.z = (short)f2bf(v.z); ob.w = (short)f2bf(v.w);
      *((short4v*)dout + (row * DIM + o) / 4) = ob;
    }
  }
}

extern "C" void kernel_launch(void* const* d_in, const int* in_sizes, int n_in,
                              void* d_out, int out_size, void* d_ws, size_t ws_size,
                              hipStream_t stream) {
  const void* h0  = d_in[0];
  const void* A_e = d_in[1];
  const void* A_c = d_in[2];
  const void* A_n = d_in[3];
  const void* W1  = d_in[4];
  const void* b1  = d_in[5];
  const void* W2  = d_in[6];
  const void* b2  = d_in[7];

  char* base = (char*)d_ws;
  size_t off = 0;
  auto take = [&](size_t n) -> char* {
    char* p = base + off; off += (n + 255) & ~(size_t)255; return p;
  };
  int*            flag = (int*)take(4);
  float*          dirs = (float*)take(3 * DIM * 4);
  float*          b1f  = (float*)take(DIM * 4);
  float*          b2f  = (float*)take(DIM * 4);
  float4*         coef = (float4*)take((size_t)BATCH * 16);
  float*          scl  = (float*)take((size_t)BATCH * 4);
  unsigned short* W1b  = (unsigned short*)take((size_t)DIM * DIM * 2);
  unsigned short* W2b  = (unsigned short*)take((size_t)DIM * DIM * 2);
  unsigned short* T    = (unsigned short*)take((size_t)BATCH * DIM * 2);
  unsigned short* hb   = (unsigned short*)take((size_t)BATCH * DIM * 2);
  float*          hf   = (float*)take((size_t)BATCH * DIM * 4);   // LAST (fallback drops it)
  const size_t need_full = off;
  const bool full = (ws_size >= need_full);

  k_detect<<<1, 64, 0, stream>>>((const unsigned short*)h0, flag);
  k_prep_w<<<dim3(4096, 2), 256, 0, stream>>>(W1, W2, flag, W1b, W2b);
  k_prep_small<<<1, 256, 0, stream>>>(b1, b2, A_e, A_c, A_n, flag, b1f, b2f, dirs);

  const dim3 gg(DIM / 256, BATCH / 256);
  if (full) {
    k_boot<1><<<BATCH, 256, 0, stream>>>(h0, flag, dirs, hf, hb, coef, scl);
    for (int L = 0; L < 4; ++L) {
      gemm_tanh<<<gg, 512, 0, stream>>>(hb, W1b, b1f, scl, T);
      gemm_update<1><<<gg, 512, 0, stream>>>(T, W2b, b2f, hf, hb, coef, dirs);
      if (L < 3) k_stats<<<BATCH/4, 256, 0, stream>>>(hb, dirs, coef, scl);
    }
    k_finish<1><<<BATCH/4, 256, 0, stream>>>(hf, hb, flag, d_out);
  } else {
    k_boot<0><<<BATCH, 256, 0, stream>>>(h0, flag, dirs, nullptr, hb, coef, scl);
    for (int L = 0; L < 4; ++L) {
      gemm_tanh<<<gg, 512, 0, stream>>>(hb, W1b, b1f, scl, T);
      gemm_update<0><<<gg, 512, 0, stream>>>(T, W2b, b2f, nullptr, hb, coef, dirs);
      if (L < 3) k_stats<<<BATCH/4, 256, 0, stream>>>(hb, dirs, coef, scl);
    }
    k_finish<0><<<BATCH/4, 256, 0, stream>>>(nullptr, hb, flag, d_out);
  }
}

// Round 2
// 1941.625 us; speedup vs baseline: 1.0362x; 1.0362x over previous
//
#include <hip/hip_runtime.h>
#include <stdint.h>

#define DIM      2048
#define BATCH    16384
#define S_E      0.1f
#define S_C      0.1f
#define S_N      0.05f
#define DIVC     0.38f
#define NCAP     10.0f

typedef __attribute__((ext_vector_type(4))) float floatx4;
typedef __attribute__((ext_vector_type(8))) short short8;
typedef __attribute__((ext_vector_type(4))) short short4v;

__device__ __forceinline__ float bf2f(unsigned short u) {
  union { float f; unsigned v; } x; x.v = ((unsigned)u) << 16; return x.f;
}
__device__ __forceinline__ unsigned short f2bf(float f) {
  union { float f; unsigned v; } x; x.f = f;
  unsigned r = x.v + 0x7FFFu + ((x.v >> 16) & 1u);   // RNE
  return (unsigned short)(r >> 16);
}

__device__ __forceinline__ void gload_lds16(const void* g, void* l) {
  __builtin_amdgcn_global_load_lds((const __attribute__((address_space(1))) void*)g,
                                   (__attribute__((address_space(3))) void*)l,
                                   16, 0, 0);
}

// ---- dtype detector: flag=1 -> fp32 inputs, flag=0 -> bf16 ----
__global__ void k_detect(const unsigned short* __restrict__ h0u, int* __restrict__ flag) {
  const int lane = threadIdx.x;
  int bad = 0;
#pragma unroll
  for (int i = 0; i < 32; ++i) {
    const unsigned u = h0u[lane + i * 64];
    const unsigned e = (u >> 7) & 0xFF;
    bad |= (e >= 0x84);
  }
  const unsigned long long m = __ballot(bad);
  if (lane == 0) *flag = (m != 0ull) ? 1 : 0;
}

__global__ __launch_bounds__(256) void k_prep_w(
    const void* __restrict__ w1r, const void* __restrict__ w2r,
    const int* __restrict__ flag,
    unsigned short* __restrict__ W1b, unsigned short* __restrict__ W2b) {
  const void* src = blockIdx.y ? w2r : w1r;
  unsigned short* dst = blockIdx.y ? W2b : W1b;
  const long i4 = (long)blockIdx.x * 256 + threadIdx.x;
  if (*flag) {
    const float4 v = ((const float4*)src)[i4];
    short4v o;
    o.x = (short)f2bf(v.x); o.y = (short)f2bf(v.y);
    o.z = (short)f2bf(v.z); o.w = (short)f2bf(v.w);
    ((short4v*)dst)[i4] = o;
  } else {
    ((short4v*)dst)[i4] = ((const short4v*)src)[i4];
  }
}

__global__ __launch_bounds__(256) void k_prep_small(
    const void* __restrict__ b1r, const void* __restrict__ b2r,
    const void* __restrict__ a0r, const void* __restrict__ a1r,
    const void* __restrict__ a2r, const int* __restrict__ flag,
    float* __restrict__ b1f, float* __restrict__ b2f, float* __restrict__ dirs) {
  __shared__ float red[4];
  const int tid = threadIdx.x, wave = tid >> 6, lane = tid & 63;
  const int isf32 = *flag;
#pragma unroll
  for (int i = 0; i < 8; ++i) {
    const int idx = i * 256 + tid;
    b1f[idx] = isf32 ? ((const float*)b1r)[idx] : bf2f(((const unsigned short*)b1r)[idx]);
    b2f[idx] = isf32 ? ((const float*)b2r)[idx] : bf2f(((const unsigned short*)b2r)[idx]);
  }
  const void* ar[3] = { a0r, a1r, a2r };
  for (int a = 0; a < 3; ++a) {
    float v[8]; float s = 0.f;
#pragma unroll
    for (int i = 0; i < 8; ++i) {
      const int idx = i * 256 + tid;
      v[i] = isf32 ? ((const float*)ar[a])[idx] : bf2f(((const unsigned short*)ar[a])[idx]);
      s = fmaf(v[i], v[i], s);
    }
#pragma unroll
    for (int off = 32; off >= 1; off >>= 1) s += __shfl_xor(s, off);
    if (lane == 0) red[wave] = s;
    __syncthreads();
    const float S = red[0] + red[1] + red[2] + red[3];
    const float inv = 1.f / fmaxf(sqrtf(S), 1e-12f);
#pragma unroll
    for (int i = 0; i < 8; ++i) dirs[a * DIM + i * 256 + tid] = v[i] * inv;
    __syncthreads();
  }
}

// coefs from CAPPED row stats (unit dirs: ||h-d||^2 = S0 - 2 h.d + 1)
__device__ __forceinline__ float4 row_coef(float S0, float Se, float Sc, float Sn) {
  const float Li = 1.f / fmaxf(sqrtf(S0), 1e-12f);
  const float ce = S_E * (DIVC - Se * Li) / fmaxf(sqrtf(fmaxf(S0 - 2.f * Se + 1.f, 0.f)), 1e-12f);
  const float cc = S_C * (DIVC - Sc * Li) / fmaxf(sqrtf(fmaxf(S0 - 2.f * Sc + 1.f, 0.f)), 1e-12f);
  const float cn = S_N * (DIVC - Sn * Li) / fmaxf(sqrtf(fmaxf(S0 - 2.f * Sn + 1.f, 0.f)), 1e-12f);
  float4 c; c.x = 1.f - (ce + cc + cn); c.y = ce; c.z = cc; c.w = cn; return c;
}

// ---- boot: h0 -> hf (FULL) + hb + coef (s=1) + scl=1 ----
template<int FULL>
__global__ __launch_bounds__(256) void k_boot(
    const void* __restrict__ h0raw, const int* __restrict__ flag,
    const float* __restrict__ dirs, float* __restrict__ hf,
    unsigned short* __restrict__ hb, float4* __restrict__ coef,
    float* __restrict__ scl) {
  __shared__ float red[16];
  const long row = blockIdx.x;
  const int tid = threadIdx.x, wave = tid >> 6, lane = tid & 63;
  const int isf32 = *flag;
  float h[8];
  float s0 = 0.f, se = 0.f, sc = 0.f, sn = 0.f;
#pragma unroll
  for (int i = 0; i < 2; ++i) {
    const int c4 = i * 256 + tid;
    float4 hv;
    if (isf32) {
      hv = ((const float4*)h0raw + row * (DIM/4))[c4];
    } else {
      const short4v hs = ((const short4v*)h0raw + row * (DIM/4))[c4];
      hv.x = bf2f((unsigned short)hs.x); hv.y = bf2f((unsigned short)hs.y);
      hv.z = bf2f((unsigned short)hs.z); hv.w = bf2f((unsigned short)hs.w);
    }
    const float4 ev = ((const float4*)dirs)[c4];
    const float4 cv = ((const float4*)(dirs + DIM))[c4];
    const float4 nv = ((const float4*)(dirs + 2*DIM))[c4];
    h[i*4+0]=hv.x; h[i*4+1]=hv.y; h[i*4+2]=hv.z; h[i*4+3]=hv.w;
    s0 = fmaf(hv.x,hv.x,fmaf(hv.y,hv.y,fmaf(hv.z,hv.z,fmaf(hv.w,hv.w,s0))));
    se = fmaf(hv.x,ev.x,fmaf(hv.y,ev.y,fmaf(hv.z,ev.z,fmaf(hv.w,ev.w,se))));
    sc = fmaf(hv.x,cv.x,fmaf(hv.y,cv.y,fmaf(hv.z,cv.z,fmaf(hv.w,cv.w,sc))));
    sn = fmaf(hv.x,nv.x,fmaf(hv.y,nv.y,fmaf(hv.z,nv.z,fmaf(hv.w,nv.w,sn))));
  }
#pragma unroll
  for (int off = 32; off >= 1; off >>= 1) {
    s0 += __shfl_xor(s0, off); se += __shfl_xor(se, off);
    sc += __shfl_xor(sc, off); sn += __shfl_xor(sn, off);
  }
  if (lane == 0) { red[wave*4+0]=s0; red[wave*4+1]=se; red[wave*4+2]=sc; red[wave*4+3]=sn; }
  __syncthreads();
  if (tid == 0) {
    const float S0 = red[0]+red[4]+red[8]+red[12];
    const float Se = red[1]+red[5]+red[9]+red[13];
    const float Sc = red[2]+red[6]+red[10]+red[14];
    const float Sn = red[3]+red[7]+red[11]+red[15];
    coef[row] = row_coef(S0, Se, Sc, Sn);   // h0 is not pre-capped; s=1
    scl[row] = 1.f;
  }
#pragma unroll
  for (int i = 0; i < 2; ++i) {
    const int c4 = i * 256 + tid;
    if (FULL) {
      float4 o; o.x=h[i*4+0]; o.y=h[i*4+1]; o.z=h[i*4+2]; o.w=h[i*4+3];
      ((float4*)hf + row * (DIM/4))[c4] = o;
    }
    short4v ob;
    ob.x=(short)f2bf(h[i*4+0]); ob.y=(short)f2bf(h[i*4+1]);
    ob.z=(short)f2bf(h[i*4+2]); ob.w=(short)f2bf(h[i*4+3]);
    ((short4v*)hb + row * (DIM/4))[c4] = ob;
  }
}

// ============================================================================
// 256x256-tile deep-pipeline GEMM core (BK=32, 4-slot LDS ring, counted vmcnt)
//
// - 512 threads = 8 waves (2 M x 4 N); each wave owns a 128x64 C-subtile.
// - LDS: 4 slots x (A 16KB + B 16KB) = 128 KB.  Slot s holds K-tile t (t&3==s)
//   as [256][32] bf16 row-major (64B rows = 4 x 16B chunks).
// - BANK-CONFLICT SWIZZLE (both-sides, T21): stored chunk c_s of row r holds
//   global chunk c_s ^ ((r>>1)&3).  gload_lds dest stays LINEAR; the swizzle
//   is applied by pre-swizzling the per-thread GLOBAL source column
//   ((tid&3) ^ ((tid>>3)&3)), and reads use qs = quad ^ ((l16>>1)&3).
//   This puts each 16-lane read-phase group across all 8 bank-groups exactly
//   2x (the free minimum) instead of 2 groups 8x (4-way conflict).
// - Pipeline: tile t's phases stage tile t+3 into slot (t+3)&3 == (t-1)&3,
//   whose reads completed before the previous boundary barrier -> race-free.
// - Boundary wait: s_waitcnt vmcnt(8), raw s_barrier (no vmcnt(0) drain).
// - 2 phases / K-tile, 16 MFMA each, s_setprio(1) around the MFMA cluster.
// ============================================================================

template<int VM, bool STG>
__device__ __forceinline__ void gemm_tile(
    const int t, const unsigned short* __restrict__ Ag,
    const unsigned short* __restrict__ Bg, char* __restrict__ smem,
    const int tid, const int wm, const int wn, const int l16, const int quad,
    floatx4 (&acc)[8][4], short8 (&bfr)[4]) {
  const int qs = (quad ^ ((l16 >> 1) & 3)) * 8;       // swizzled chunk (shorts)
  const short* As = (const short*)(smem + (t & 3) * 32768) + (wm + l16) * 32 + qs;
  const short* Bs = (const short*)(smem + (t & 3) * 32768 + 16384) + (wn + l16) * 32 + qs;
  // ---- phase A: read B-frags + A-frags 0..3, stage A(t+3), MFMA upper half ----
  short8 af[4];
#pragma unroll
  for (int j = 0; j < 4; ++j) bfr[j] = *(const short8*)(Bs + j * 512);
#pragma unroll
  for (int i = 0; i < 4; ++i) af[i] = *(const short8*)(As + i * 512);
  if (STG) {
    const unsigned short* as = Ag + (t + 3) * 32;
    char* dA = smem + ((t + 3) & 3) * 32768 + tid * 16;
    gload_lds16(as, dA);
    gload_lds16(as + (size_t)128 * DIM, dA + 8192);
  }
  __builtin_amdgcn_s_barrier();
  __builtin_amdgcn_sched_barrier(0);
  __builtin_amdgcn_s_setprio(1);
#pragma unroll
  for (int i = 0; i < 4; ++i)
#pragma unroll
    for (int j = 0; j < 4; ++j)
      acc[i][j] = __builtin_amdgcn_mfma_f32_16x16x32_bf16(af[i], bfr[j], acc[i][j], 0, 0, 0);
  __builtin_amdgcn_s_setprio(0);
  __builtin_amdgcn_s_barrier();
  __builtin_amdgcn_sched_barrier(0);
  // ---- phase B: read A-frags 4..7, stage B(t+3), MFMA lower half ----
#pragma unroll
  for (int i = 0; i < 4; ++i) af[i] = *(const short8*)(As + (4 + i) * 512);
  if (STG) {
    const unsigned short* bs = Bg + (t + 3) * 32;
    char* dB = smem + ((t + 3) & 3) * 32768 + 16384 + tid * 16;
    gload_lds16(bs, dB);
    gload_lds16(bs + (size_t)128 * DIM, dB + 8192);
  }
  __builtin_amdgcn_s_barrier();
  __builtin_amdgcn_sched_barrier(0);
  __builtin_amdgcn_s_setprio(1);
#pragma unroll
  for (int i = 0; i < 4; ++i)
#pragma unroll
    for (int j = 0; j < 4; ++j)
      acc[4 + i][j] = __builtin_amdgcn_mfma_f32_16x16x32_bf16(af[i], bfr[j], acc[4 + i][j], 0, 0, 0);
  __builtin_amdgcn_s_setprio(0);
  __builtin_amdgcn_sched_barrier(0);
  // ---- K-tile boundary: counted wait (tile t+1 landed), never drain mid-loop
  if constexpr (VM == 8)      asm volatile("s_waitcnt vmcnt(8)" ::: "memory");
  else if constexpr (VM == 4) asm volatile("s_waitcnt vmcnt(4)" ::: "memory");
  else if constexpr (VM == 0) asm volatile("s_waitcnt vmcnt(0)" ::: "memory");
  __builtin_amdgcn_s_barrier();
  __builtin_amdgcn_sched_barrier(0);
}

__device__ __forceinline__ void gemm_main(
    const unsigned short* __restrict__ A, const unsigned short* __restrict__ B,
    char* __restrict__ smem, const int tid, const int wm, const int wn,
    const int l16, const int quad, const long m0, const long n0,
    floatx4 (&acc)[8][4]) {
  // stage addressing: LDS byte tid*16 = (row tid>>2, stored chunk tid&3);
  // global source column is PRE-SWIZZLED: c_g = (tid&3) ^ ((row>>1)&3), row=tid>>2
  const int csw = ((tid & 3) ^ ((tid >> 3) & 3)) * 8;
  const unsigned short* Ag = A + (m0 + (tid >> 2)) * DIM + csw;
  const unsigned short* Bg = B + (n0 + (tid >> 2)) * DIM + csw;
  // prologue: stage tiles 0,1,2 (12 loads/thread-group)
#pragma unroll
  for (int tt = 0; tt < 3; ++tt) {
    const unsigned short* as = Ag + tt * 32;
    const unsigned short* bs = Bg + tt * 32;
    char* dA = smem + tt * 32768 + tid * 16;
    char* dB = dA + 16384;
    gload_lds16(as, dA);
    gload_lds16(as + (size_t)128 * DIM, dA + 8192);
    gload_lds16(bs, dB);
    gload_lds16(bs + (size_t)128 * DIM, dB + 8192);
  }
  asm volatile("s_waitcnt vmcnt(8)" ::: "memory");   // tile 0 landed; 1,2 in flight
  __builtin_amdgcn_s_barrier();
  __builtin_amdgcn_sched_barrier(0);
  short8 bfr[4];
#pragma unroll 1
  for (int t = 0; t < DIM / 32 - 3; ++t)
    gemm_tile<8, true >(t, Ag, Bg, smem, tid, wm, wn, l16, quad, acc, bfr);
  gemm_tile<4, false>(DIM / 32 - 3, Ag, Bg, smem, tid, wm, wn, l16, quad, acc, bfr);
  gemm_tile<0, false>(DIM / 32 - 2, Ag, Bg, smem, tid, wm, wn, l16, quad, acc, bfr);
  gemm_tile<-1, false>(DIM / 32 - 1, Ag, Bg, smem, tid, wm, wn, l16, quad, acc, bfr);
}

// XCD-aware bijective block swizzle: 512 wg, 8 XCDs, n-tile fastest per XCD
__device__ __forceinline__ void xcd_tiles(long& m0, long& n0) {
  const int b = blockIdx.y * (DIM / 256) + blockIdx.x;     // 0..511
  const int swz = (b & 7) * ((BATCH / 256) * (DIM / 256) / 8) + (b >> 3);
  m0 = (long)(swz >> 3) * 256;                             // 8 n-tiles
  n0 = (long)(swz & 7) * 256;
}

// ---- GEMM1: T = tanh(scl[row]*(hb @ W1^T) + b1) ----
__global__ __launch_bounds__(512, 2) void gemm_tanh(
    const unsigned short* __restrict__ A, const unsigned short* __restrict__ B,
    const float* __restrict__ bias, const float* __restrict__ scl,
    unsigned short* __restrict__ Cb) {
  __shared__ __align__(16) char smem[131072];
  const int tid = threadIdx.x, wave = tid >> 6, lane = tid & 63;
  const int quad = lane >> 4, l16 = lane & 15;
  const int wm = (wave >> 2) * 128, wn = (wave & 3) * 64;
  long m0, n0;
  xcd_tiles(m0, n0);
  floatx4 acc[8][4] = {};
  gemm_main(A, B, smem, tid, wm, wn, l16, quad, m0, n0, acc);
  __syncthreads();
  asm volatile("" ::: "memory");
  // epilogue: scale rows, bias, tanh -> bf16 into LDS, then coalesced stores
  short* Eh = (short*)smem;           // [256][256] bf16 = 128KB
  float sr[32];
#pragma unroll
  for (int i = 0; i < 8; ++i) {
    const float4 s4 = *(const float4*)(scl + m0 + wm + i * 16 + quad * 4);
    sr[i*4+0] = s4.x; sr[i*4+1] = s4.y; sr[i*4+2] = s4.z; sr[i*4+3] = s4.w;
  }
  float bcol[4];
#pragma unroll
  for (int j = 0; j < 4; ++j) bcol[j] = bias[n0 + wn + j * 16 + l16];
#pragma unroll
  for (int i = 0; i < 8; ++i) {
    const int row = wm + i * 16 + quad * 4;
#pragma unroll
    for (int j = 0; j < 4; ++j) {
      const int col = wn + j * 16 + l16;
#pragma unroll
      for (int r = 0; r < 4; ++r) {
        const float x = fmaf(sr[i*4+r], acc[i][j][r], bcol[j]);
        const float tt = 1.f - 2.f / (__expf(2.f * x) + 1.f);
        Eh[(row + r) * 256 + col] = (short)f2bf(tt);
      }
    }
  }
  __syncthreads();
#pragma unroll
  for (int s = 0; s < 16; ++s) {
    const int g = s * 512 + tid;
    const int row = g >> 5, c8 = (g & 31) * 8;
    *(short8*)(Cb + (m0 + row) * DIM + n0 + c8) = *(const short8*)(Eh + row * 256 + c8);
  }
}

// ---- GEMM2 + fused collapse update (uncapped h master; cf.x = ch*s folded) ----
template<int FULL>
__global__ __launch_bounds__(512, 2) void gemm_update(
    const unsigned short* __restrict__ A, const unsigned short* __restrict__ B,
    const float* __restrict__ bias, float* __restrict__ hf,
    unsigned short* __restrict__ hb, const float4* __restrict__ coef,
    const float* __restrict__ dirs) {
  __shared__ __align__(16) char smem[131072];
  const int tid = threadIdx.x, wave = tid >> 6, lane = tid & 63;
  const int quad = lane >> 4, l16 = lane & 15;
  const int wm = (wave >> 2) * 128, wn = (wave & 3) * 64;
  long m0, n0;
  xcd_tiles(m0, n0);
  floatx4 acc[8][4] = {};
  gemm_main(A, B, smem, tid, wm, wn, l16, quad, m0, n0, acc);
  asm volatile("" ::: "memory");
  // two j-half passes through LDS (fp32); coalesced float4 RMW of hf + hb mirror
  float* Ef = (float*)smem;           // [256][128] fp32 = 128KB
#pragma unroll
  for (int p = 0; p < 2; ++p) {
    __syncthreads();
#pragma unroll
    for (int i = 0; i < 8; ++i) {
      const int row = wm + i * 16 + quad * 4;
#pragma unroll
      for (int jj = 0; jj < 2; ++jj) {
        const int cc = (wn >> 1) + jj * 16 + l16;       // wave's 32-col stripe pair
#pragma unroll
        for (int r = 0; r < 4; ++r)
          Ef[(row + r) * 128 + cc] = acc[i][p * 2 + jj][r];
      }
    }
    __syncthreads();
#pragma unroll
    for (int s = 0; s < 16; ++s) {
      const int q = s * 512 + tid;
      const int row = q >> 5, c4 = (q & 31) * 4;
      const int col = ((c4 >> 5) * 64) + p * 32 + (c4 & 31);  // de-compact 32-stripes
      const long gr = m0 + row, gc = n0 + col;
      const float4 e  = *(const float4*)(Ef + row * 128 + c4);
      const float4 bv = *(const float4*)(bias + gc);
      const float4 de = *(const float4*)(dirs + gc);
      const float4 dc = *(const float4*)(dirs + DIM + gc);
      const float4 dn = *(const float4*)(dirs + 2*DIM + gc);
      const float4 cf = coef[gr];
      float4 hv;
      if (FULL) {
        hv = *(const float4*)(hf + gr * DIM + gc);
      } else {
        const short4v hs = *(const short4v*)(hb + gr * DIM + gc);
        hv.x = bf2f((unsigned short)hs.x); hv.y = bf2f((unsigned short)hs.y);
        hv.z = bf2f((unsigned short)hs.z); hv.w = bf2f((unsigned short)hs.w);
      }
      float4 v;
      v.x = e.x + bv.x; v.y = e.y + bv.y; v.z = e.z + bv.z; v.w = e.w + bv.w;
      v.x = fmaf(cf.x, hv.x, v.x); v.y = fmaf(cf.x, hv.y, v.y);
      v.z = fmaf(cf.x, hv.z, v.z); v.w = fmaf(cf.x, hv.w, v.w);
      v.x = fmaf(cf.y, de.x, v.x); v.y = fmaf(cf.y, de.y, v.y);
      v.z = fmaf(cf.y, de.z, v.z); v.w = fmaf(cf.y, de.w, v.w);
      v.x = fmaf(cf.z, dc.x, v.x); v.y = fmaf(cf.z, dc.y, v.y);
      v.z = fmaf(cf.z, dc.z, v.z); v.w = fmaf(cf.z, dc.w, v.w);
      v.x = fmaf(cf.w, dn.x, v.x); v.y = fmaf(cf.w, dn.y, v.y);
      v.z = fmaf(cf.w, dn.z, v.z); v.w = fmaf(cf.w, dn.w, v.w);
      if (FULL) *(float4*)(hf + gr * DIM + gc) = v;
      short4v ob;
      ob.x = (short)f2bf(v.x); ob.y = (short)f2bf(v.y);
      ob.z = (short)f2bf(v.z); ob.w = (short)f2bf(v.w);
      *(short4v*)(hb + gr * DIM + gc) = ob;
    }
  }
}

// ---- stats: read hb (uncapped), emit next-layer coef (cf.x=ch*s) + scl=s ----
__global__ __launch_bounds__(256) void k_stats(
    const unsigned short* __restrict__ hb, const float* __restrict__ dirs,
    float4* __restrict__ coef, float* __restrict__ scl) {
  const int tid = threadIdx.x, w = tid >> 6, lane = tid & 63;
  const long row = (long)blockIdx.x * 4 + w;
  const unsigned short* hr = hb + row * DIM;
  float s0 = 0.f, se = 0.f, sc = 0.f, sn = 0.f;
#pragma unroll
  for (int i = 0; i < 4; ++i) {
    const int o = i * 512 + lane * 8;
    const short8 h8 = *(const short8*)(hr + o);
    float h[8];
#pragma unroll
    for (int q = 0; q < 8; ++q) h[q] = bf2f((unsigned short)h8[q]);
    const float4 e0 = *(const float4*)(dirs + o),       e1 = *(const float4*)(dirs + o + 4);
    const float4 c0 = *(const float4*)(dirs + DIM + o), c1 = *(const float4*)(dirs + DIM + o + 4);
    const float4 n0v = *(const float4*)(dirs + 2*DIM + o), n1 = *(const float4*)(dirs + 2*DIM + o + 4);
    const float ee[8] = { e0.x,e0.y,e0.z,e0.w, e1.x,e1.y,e1.z,e1.w };
    const float ccv[8] = { c0.x,c0.y,c0.z,c0.w, c1.x,c1.y,c1.z,c1.w };
    const float nn[8] = { n0v.x,n0v.y,n0v.z,n0v.w, n1.x,n1.y,n1.z,n1.w };
#pragma unroll
    for (int q = 0; q < 8; ++q) {
      s0 = fmaf(h[q], h[q], s0);
      se = fmaf(h[q], ee[q], se);
      sc = fmaf(h[q], ccv[q], sc);
      sn = fmaf(h[q], nn[q], sn);
    }
  }
#pragma unroll
  for (int off = 32; off >= 1; off >>= 1) {
    s0 += __shfl_xor(s0, off); se += __shfl_xor(se, off);
    sc += __shfl_xor(sc, off); sn += __shfl_xor(sn, off);
  }
  if (lane == 0) {
    const float nrm = sqrtf(s0);
    const float s = (nrm > NCAP) ? (NCAP / (nrm + 1e-8f)) : 1.f;
    float4 cf = row_coef(s0 * s * s, se * s, sc * s, sn * s);
    cf.x *= s;                       // applied to UNCAPPED h master
    coef[row] = cf;
    scl[row] = s;
  }
}

// ---- finish: norm-cap final h_pre, write d_out (dtype by flag) ----
template<int FULL>
__global__ __launch_bounds__(256) void k_finish(
    const float* __restrict__ hf, const unsigned short* __restrict__ hb,
    const int* __restrict__ flag, void* __restrict__ dout) {
  const int tid = threadIdx.x, w = tid >> 6, lane = tid & 63;
  const long row = (long)blockIdx.x * 4 + w;
  float4 hv[8];
  float s0 = 0.f;
#pragma unroll
  for (int i = 0; i < 8; ++i) {
    const int o = i * 256 + lane * 4;
    if (FULL) {
      hv[i] = *(const float4*)(hf + row * DIM + o);
    } else {
      const short4v hs = *(const short4v*)(hb + row * DIM + o);
      hv[i].x = bf2f((unsigned short)hs.x); hv[i].y = bf2f((unsigned short)hs.y);
      hv[i].z = bf2f((unsigned short)hs.z); hv[i].w = bf2f((unsigned short)hs.w);
    }
    s0 = fmaf(hv[i].x,hv[i].x,fmaf(hv[i].y,hv[i].y,fmaf(hv[i].z,hv[i].z,fmaf(hv[i].w,hv[i].w,s0))));
  }
#pragma unroll
  for (int off = 32; off >= 1; off >>= 1) s0 += __shfl_xor(s0, off);
  const float nrm = sqrtf(s0);
  const float s = (nrm > NCAP) ? (NCAP / (nrm + 1e-8f)) : 1.f;
  const int isf32 = *flag;
#pragma unroll
  for (int i = 0; i < 8; ++i) {
    const int o = i * 256 + lane * 4;
    float4 v;
    v.x = hv[i].x * s; v.y = hv[i].y * s; v.z = hv[i].z * s; v.w = hv[i].w * s;
    if (isf32) {
      *((float4*)dout + (row * DIM + o) / 4) = v;
    } else {
      short4v ob;
      ob.x = (short)f2bf(v.x); ob.y = (short)f2bf(v.y);
      ob.z = (short)f2bf(v.z); ob.w = (short)f2bf(v.w);
      *((short4v*)dout + (row * DIM + o) / 4) = ob;
    }
  }
}

extern "C" void kernel_launch(void* const* d_in, const int* in_sizes, int n_in,
                              void* d_out, int out_size, void* d_ws, size_t ws_size,
                              hipStream_t stream) {
  const void* h0  = d_in[0];
  const void* A_e = d_in[1];
  const void* A_c = d_in[2];
  const void* A_n = d_in[3];
  const void* W1  = d_in[4];
  const void* b1  = d_in[5];
  const void* W2  = d_in[6];
  const void* b2  = d_in[7];

  char* base = (char*)d_ws;
  size_t off = 0;
  auto take = [&](size_t n) -> char* {
    char* p = base + off; off += (n + 255) & ~(size_t)255; return p;
  };
  int*            flag = (int*)take(4);
  float*          dirs = (float*)take(3 * DIM * 4);
  float*          b1f  = (float*)take(DIM * 4);
  float*          b2f  = (float*)take(DIM * 4);
  float4*         coef = (float4*)take((size_t)BATCH * 16);
  float*          scl  = (float*)take((size_t)BATCH * 4);
  unsigned short* W1b  = (unsigned short*)take((size_t)DIM * DIM * 2);
  unsigned short* W2b  = (unsigned short*)take((size_t)DIM * DIM * 2);
  unsigned short* T    = (unsigned short*)take((size_t)BATCH * DIM * 2);
  unsigned short* hb   = (unsigned short*)take((size_t)BATCH * DIM * 2);
  float*          hf   = (float*)take((size_t)BATCH * DIM * 4);   // LAST (fallback drops it)
  const size_t need_full = off;
  const bool full = (ws_size >= need_full);

  k_detect<<<1, 64, 0, stream>>>((const unsigned short*)h0, flag);
  k_prep_w<<<dim3(4096, 2), 256, 0, stream>>>(W1, W2, flag, W1b, W2b);
  k_prep_small<<<1, 256, 0, stream>>>(b1, b2, A_e, A_c, A_n, flag, b1f, b2f, dirs);

  const dim3 gg(DIM / 256, BATCH / 256);
  if (full) {
    k_boot<1><<<BATCH, 256, 0, stream>>>(h0, flag, dirs, hf, hb, coef, scl);
    for (int L = 0; L < 4; ++L) {
      gemm_tanh<<<gg, 512, 0, stream>>>(hb, W1b, b1f, scl, T);
      gemm_update<1><<<gg, 512, 0, stream>>>(T, W2b, b2f, hf, hb, coef, dirs);
      if (L < 3) k_stats<<<BATCH/4, 256, 0, stream>>>(hb, dirs, coef, scl);
    }
    k_finish<1><<<BATCH/4, 256, 0, stream>>>(hf, hb, flag, d_out);
  } else {
    k_boot<0><<<BATCH, 256, 0, stream>>>(h0, flag, dirs, nullptr, hb, coef, scl);
    for (int L = 0; L < 4; ++L) {
      gemm_tanh<<<gg, 512, 0, stream>>>(hb, W1b, b1f, scl, T);
      gemm_update<0><<<gg, 512, 0, stream>>>(T, W2b, b2f, nullptr, hb, coef, dirs);
      if (L < 3) k_stats<<<BATCH/4, 256, 0, stream>>>(hb, dirs, coef, scl);
    }
    k_finish<0><<<BATCH/4, 256, 0, stream>>>(nullptr, hb, flag, d_out);
  }
}

// Round 3
// 1864.197 us; speedup vs baseline: 1.0793x; 1.0415x over previous
//
#include <hip/hip_runtime.h>
#include <stdint.h>

#define DIM      2048
#define BATCH    16384
#define S_E      0.1f
#define S_C      0.1f
#define S_N      0.05f
#define DIVC     0.38f
#define NCAP     10.0f

typedef __attribute__((ext_vector_type(4))) float floatx4;
typedef __attribute__((ext_vector_type(8))) short short8;
typedef __attribute__((ext_vector_type(4))) short short4v;

__device__ __forceinline__ float bf2f(unsigned short u) {
  union { float f; unsigned v; } x; x.v = ((unsigned)u) << 16; return x.f;
}
__device__ __forceinline__ unsigned short f2bf(float f) {
  union { float f; unsigned v; } x; x.f = f;
  unsigned r = x.v + 0x7FFFu + ((x.v >> 16) & 1u);   // RNE
  return (unsigned short)(r >> 16);
}

__device__ __forceinline__ void gload_lds16(const void* g, void* l) {
  __builtin_amdgcn_global_load_lds((const __attribute__((address_space(1))) void*)g,
                                   (__attribute__((address_space(3))) void*)l,
                                   16, 0, 0);
}

// ---- dtype detector: flag=1 -> fp32 inputs, flag=0 -> bf16 ----
__global__ void k_detect(const unsigned short* __restrict__ h0u, int* __restrict__ flag) {
  const int lane = threadIdx.x;
  int bad = 0;
#pragma unroll
  for (int i = 0; i < 32; ++i) {
    const unsigned u = h0u[lane + i * 64];
    const unsigned e = (u >> 7) & 0xFF;
    bad |= (e >= 0x84);
  }
  const unsigned long long m = __ballot(bad);
  if (lane == 0) *flag = (m != 0ull) ? 1 : 0;
}

__global__ __launch_bounds__(256) void k_prep_w(
    const void* __restrict__ w1r, const void* __restrict__ w2r,
    const int* __restrict__ flag,
    unsigned short* __restrict__ W1b, unsigned short* __restrict__ W2b) {
  const void* src = blockIdx.y ? w2r : w1r;
  unsigned short* dst = blockIdx.y ? W2b : W1b;
  const long i4 = (long)blockIdx.x * 256 + threadIdx.x;
  if (*flag) {
    const float4 v = ((const float4*)src)[i4];
    short4v o;
    o.x = (short)f2bf(v.x); o.y = (short)f2bf(v.y);
    o.z = (short)f2bf(v.z); o.w = (short)f2bf(v.w);
    ((short4v*)dst)[i4] = o;
  } else {
    ((short4v*)dst)[i4] = ((const short4v*)src)[i4];
  }
}

__global__ __launch_bounds__(256) void k_prep_small(
    const void* __restrict__ b1r, const void* __restrict__ b2r,
    const void* __restrict__ a0r, const void* __restrict__ a1r,
    const void* __restrict__ a2r, const int* __restrict__ flag,
    float* __restrict__ b1f, float* __restrict__ b2f, float* __restrict__ dirs) {
  __shared__ float red[4];
  const int tid = threadIdx.x, wave = tid >> 6, lane = tid & 63;
  const int isf32 = *flag;
#pragma unroll
  for (int i = 0; i < 8; ++i) {
    const int idx = i * 256 + tid;
    b1f[idx] = isf32 ? ((const float*)b1r)[idx] : bf2f(((const unsigned short*)b1r)[idx]);
    b2f[idx] = isf32 ? ((const float*)b2r)[idx] : bf2f(((const unsigned short*)b2r)[idx]);
  }
  const void* ar[3] = { a0r, a1r, a2r };
  for (int a = 0; a < 3; ++a) {
    float v[8]; float s = 0.f;
#pragma unroll
    for (int i = 0; i < 8; ++i) {
      const int idx = i * 256 + tid;
      v[i] = isf32 ? ((const float*)ar[a])[idx] : bf2f(((const unsigned short*)ar[a])[idx]);
      s = fmaf(v[i], v[i], s);
    }
#pragma unroll
    for (int off = 32; off >= 1; off >>= 1) s += __shfl_xor(s, off);
    if (lane == 0) red[wave] = s;
    __syncthreads();
    const float S = red[0] + red[1] + red[2] + red[3];
    const float inv = 1.f / fmaxf(sqrtf(S), 1e-12f);
#pragma unroll
    for (int i = 0; i < 8; ++i) dirs[a * DIM + i * 256 + tid] = v[i] * inv;
    __syncthreads();
  }
}

// coefs from CAPPED row stats (unit dirs: ||h-d||^2 = S0 - 2 h.d + 1)
__device__ __forceinline__ float4 row_coef(float S0, float Se, float Sc, float Sn) {
  const float Li = 1.f / fmaxf(sqrtf(S0), 1e-12f);
  const float ce = S_E * (DIVC - Se * Li) / fmaxf(sqrtf(fmaxf(S0 - 2.f * Se + 1.f, 0.f)), 1e-12f);
  const float cc = S_C * (DIVC - Sc * Li) / fmaxf(sqrtf(fmaxf(S0 - 2.f * Sc + 1.f, 0.f)), 1e-12f);
  const float cn = S_N * (DIVC - Sn * Li) / fmaxf(sqrtf(fmaxf(S0 - 2.f * Sn + 1.f, 0.f)), 1e-12f);
  float4 c; c.x = 1.f - (ce + cc + cn); c.y = ce; c.z = cc; c.w = cn; return c;
}

// ---- boot: h0 -> hf (FULL) + hb + coef (s=1) + scl=1 ----
template<int FULL>
__global__ __launch_bounds__(256) void k_boot(
    const void* __restrict__ h0raw, const int* __restrict__ flag,
    const float* __restrict__ dirs, float* __restrict__ hf,
    unsigned short* __restrict__ hb, float4* __restrict__ coef,
    float* __restrict__ scl) {
  __shared__ float red[16];
  const long row = blockIdx.x;
  const int tid = threadIdx.x, wave = tid >> 6, lane = tid & 63;
  const int isf32 = *flag;
  float h[8];
  float s0 = 0.f, se = 0.f, sc = 0.f, sn = 0.f;
#pragma unroll
  for (int i = 0; i < 2; ++i) {
    const int c4 = i * 256 + tid;
    float4 hv;
    if (isf32) {
      hv = ((const float4*)h0raw + row * (DIM/4))[c4];
    } else {
      const short4v hs = ((const short4v*)h0raw + row * (DIM/4))[c4];
      hv.x = bf2f((unsigned short)hs.x); hv.y = bf2f((unsigned short)hs.y);
      hv.z = bf2f((unsigned short)hs.z); hv.w = bf2f((unsigned short)hs.w);
    }
    const float4 ev = ((const float4*)dirs)[c4];
    const float4 cv = ((const float4*)(dirs + DIM))[c4];
    const float4 nv = ((const float4*)(dirs + 2*DIM))[c4];
    h[i*4+0]=hv.x; h[i*4+1]=hv.y; h[i*4+2]=hv.z; h[i*4+3]=hv.w;
    s0 = fmaf(hv.x,hv.x,fmaf(hv.y,hv.y,fmaf(hv.z,hv.z,fmaf(hv.w,hv.w,s0))));
    se = fmaf(hv.x,ev.x,fmaf(hv.y,ev.y,fmaf(hv.z,ev.z,fmaf(hv.w,ev.w,se))));
    sc = fmaf(hv.x,cv.x,fmaf(hv.y,cv.y,fmaf(hv.z,cv.z,fmaf(hv.w,cv.w,sc))));
    sn = fmaf(hv.x,nv.x,fmaf(hv.y,nv.y,fmaf(hv.z,nv.z,fmaf(hv.w,nv.w,sn))));
  }
#pragma unroll
  for (int off = 32; off >= 1; off >>= 1) {
    s0 += __shfl_xor(s0, off); se += __shfl_xor(se, off);
    sc += __shfl_xor(sc, off); sn += __shfl_xor(sn, off);
  }
  if (lane == 0) { red[wave*4+0]=s0; red[wave*4+1]=se; red[wave*4+2]=sc; red[wave*4+3]=sn; }
  __syncthreads();
  if (tid == 0) {
    const float S0 = red[0]+red[4]+red[8]+red[12];
    const float Se = red[1]+red[5]+red[9]+red[13];
    const float Sc = red[2]+red[6]+red[10]+red[14];
    const float Sn = red[3]+red[7]+red[11]+red[15];
    coef[row] = row_coef(S0, Se, Sc, Sn);   // h0 is not pre-capped; s=1
    scl[row] = 1.f;
  }
#pragma unroll
  for (int i = 0; i < 2; ++i) {
    const int c4 = i * 256 + tid;
    if (FULL) {
      float4 o; o.x=h[i*4+0]; o.y=h[i*4+1]; o.z=h[i*4+2]; o.w=h[i*4+3];
      ((float4*)hf + row * (DIM/4))[c4] = o;
    }
    short4v ob;
    ob.x=(short)f2bf(h[i*4+0]); ob.y=(short)f2bf(h[i*4+1]);
    ob.z=(short)f2bf(h[i*4+2]); ob.w=(short)f2bf(h[i*4+3]);
    ((short4v*)hb + row * (DIM/4))[c4] = ob;
  }
}

// ============================================================================
// 256x256-tile GEMM core — m201-style 8-phase schedule (T3+T4+T2+T5).
//
// - 512 threads = 8 waves (2M x 4N); wave owns 128x64 C.  BK=64.
// - LDS 128KB: A0[0,32K) B0[32K,64K) A1[64K,96K) B1[96K,128K); [256][64] bf16,
//   128B rows, chunk-swizzled: stored 16B-chunk cs of row r holds global chunk
//   cs ^ (r&7).  gload_lds dest linear; swizzle via pre-swizzled global col
//   ((tid&7)^((tid>>3)&7)); reads XOR (l16&7).  2 lanes/bank per quarter = free.
// - Iter = 2 K-tiles (t even in buf0, t+1 in buf1), 8 phases, each:
//   {ds_reads ; 2 gload_lds ; barrier ; lgkmcnt(0) ; setprio1 ; 16 MFMA
//    (one C-quadrant x K=64) ; setprio0 ; [vmcnt(4) @P4/P8] ; barrier}.
// - Quadrant order per tile: (ih,jh) = (0,0),(1,0),(0,1),(1,1); A-halves kept
//   in regs (a0,a1) so A-LDS dead after P2, B-LDS dead after P3.
// - Stage slots (targets provably dead, vmcnt uniform 2/phase):
//   P1,P2: B(t+1)->B1   P3,P4: A(t+2)->A0   P5,P6: B(t+2)->B0
//   P7,P8: A(t+3)->A1.  vmcnt(4) at P4 (t+1 landed) and P8 (t+2 landed).
// - Tail: stage source k clamped to tile 31 (dest regions dead; data unused).
// ============================================================================

__device__ __forceinline__ void gemm_main(
    const unsigned short* __restrict__ A, const unsigned short* __restrict__ B,
    char* __restrict__ smem, const int tid, const int wm, const int wn,
    const int l16, const int quad, const long m0, const long n0,
    floatx4 (&acc)[8][4]) {
  const int s3 = l16 & 7;
  const int csw = ((tid & 7) ^ ((tid >> 3) & 7)) * 8;
  const unsigned short* Ag = A + (m0 + (tid >> 3)) * DIM + csw;
  const unsigned short* Bg = B + (n0 + (tid >> 3)) * DIM + csw;
  short* lds = (short*)smem;
  const int ao0 = (wm + l16) * 64 + ((quad ^ s3)) * 8;
  const int ao1 = (wm + l16) * 64 + (((quad + 4) ^ s3)) * 8;
  const int bo0 = (wn + l16) * 64 + ((quad ^ s3)) * 8;
  const int bo1 = (wn + l16) * 64 + (((quad + 4) ^ s3)) * 8;

#define STAGE_A(dbuf, ts, h) { \
    const unsigned short* s_ = Ag + (size_t)((h) * 128) * DIM + (ts) * 64; \
    char* d_ = smem + (dbuf) * 65536 + (h) * 16384 + tid * 16; \
    gload_lds16(s_, d_); gload_lds16(s_ + (size_t)64 * DIM, d_ + 8192); }
#define STAGE_B(dbuf, ts, h) { \
    const unsigned short* s_ = Bg + (size_t)((h) * 128) * DIM + (ts) * 64; \
    char* d_ = smem + (dbuf) * 65536 + 32768 + (h) * 16384 + tid * 16; \
    gload_lds16(s_, d_); gload_lds16(s_ + (size_t)64 * DIM, d_ + 8192); }
#define RD_A(dst, bufo, ih) { \
    _Pragma("unroll") for (int i_ = 0; i_ < 4; ++i_) { \
      dst[i_][0] = *(const short8*)(lds + (bufo) + (ih) * 4096 + i_ * 1024 + ao0); \
      dst[i_][1] = *(const short8*)(lds + (bufo) + (ih) * 4096 + i_ * 1024 + ao1); } }
#define RD_B(bufo, jh) { \
    _Pragma("unroll") for (int j_ = 0; j_ < 2; ++j_) { \
      bR[j_][0] = *(const short8*)(lds + (bufo) + 16384 + (jh) * 2048 + j_ * 1024 + bo0); \
      bR[j_][1] = *(const short8*)(lds + (bufo) + 16384 + (jh) * 2048 + j_ * 1024 + bo1); } }
#define MF(ih, jh, aR) \
    __builtin_amdgcn_sched_barrier(0); \
    __builtin_amdgcn_s_barrier(); \
    asm volatile("s_waitcnt lgkmcnt(0)" ::: "memory"); \
    __builtin_amdgcn_sched_barrier(0); \
    __builtin_amdgcn_s_setprio(1); \
    _Pragma("unroll") for (int i_ = 0; i_ < 4; ++i_) \
    _Pragma("unroll") for (int j_ = 0; j_ < 2; ++j_) { \
      acc[(ih)*4+i_][(jh)*2+j_] = __builtin_amdgcn_mfma_f32_16x16x32_bf16(aR[i_][0], bR[j_][0], acc[(ih)*4+i_][(jh)*2+j_], 0, 0, 0); \
      acc[(ih)*4+i_][(jh)*2+j_] = __builtin_amdgcn_mfma_f32_16x16x32_bf16(aR[i_][1], bR[j_][1], acc[(ih)*4+i_][(jh)*2+j_], 0, 0, 0); } \
    __builtin_amdgcn_s_setprio(0); \
    __builtin_amdgcn_sched_barrier(0);
#define ENDPH    { __builtin_amdgcn_s_barrier(); __builtin_amdgcn_sched_barrier(0); }
#define ENDPH_VM { asm volatile("s_waitcnt vmcnt(4)" ::: "memory"); \
                   __builtin_amdgcn_s_barrier(); __builtin_amdgcn_sched_barrier(0); }

  short8 a0[4][2], a1[4][2], bR[2][2];
  // prologue: A(0)->A0, B(0)->B0, A(1)->A1 (12 loads); wait tile0 (leave A(1))
  STAGE_A(0, 0, 0); STAGE_A(0, 0, 1);
  STAGE_B(0, 0, 0); STAGE_B(0, 0, 1);
  STAGE_A(1, 1, 0); STAGE_A(1, 1, 1);
  asm volatile("s_waitcnt vmcnt(4)" ::: "memory");
  __builtin_amdgcn_s_barrier();
  __builtin_amdgcn_sched_barrier(0);

#pragma unroll 1
  for (int it = 0; it < DIM / 128; ++it) {
    const int t = it * 2;
    const int t2 = (t + 2 < 31) ? (t + 2) : 31;
    const int t3 = (t + 3 < 31) ? (t + 3) : 31;
    // P1: Q(0,0) tile t
    RD_A(a0, 0, 0); RD_B(0, 0); STAGE_B(1, t + 1, 0);
    MF(0, 0, a0) ENDPH
    // P2: Q(1,0)
    RD_A(a1, 0, 1); STAGE_B(1, t + 1, 1);
    MF(1, 0, a1) ENDPH
    // P3: Q(0,1)
    RD_B(0, 1); STAGE_A(0, t2, 0);
    MF(0, 1, a0) ENDPH
    // P4: Q(1,1)  [boundary: t+1 landed]
    STAGE_A(0, t2, 1);
    MF(1, 1, a1) ENDPH_VM
    // P5: Q(0,0) tile t+1
    RD_A(a0, 32768, 0); RD_B(32768, 0); STAGE_B(0, t2, 0);
    MF(0, 0, a0) ENDPH
    // P6: Q(1,0)
    RD_A(a1, 32768, 1); STAGE_B(0, t2, 1);
    MF(1, 0, a1) ENDPH
    // P7: Q(0,1)
    RD_B(32768, 1); STAGE_A(1, t3, 0);
    MF(0, 1, a0) ENDPH
    // P8: Q(1,1)  [boundary: t+2 landed]
    STAGE_A(1, t3, 1);
    MF(1, 1, a1) ENDPH_VM
  }
#undef STAGE_A
#undef STAGE_B
#undef RD_A
#undef RD_B
#undef MF
#undef ENDPH
#undef ENDPH_VM
}

// XCD-aware bijective block swizzle: 512 wg, 8 XCDs, n-tile fastest per XCD
__device__ __forceinline__ void xcd_tiles(long& m0, long& n0) {
  const int b = blockIdx.y * (DIM / 256) + blockIdx.x;     // 0..511
  const int swz = (b & 7) * ((BATCH / 256) * (DIM / 256) / 8) + (b >> 3);
  m0 = (long)(swz >> 3) * 256;                             // 8 n-tiles
  n0 = (long)(swz & 7) * 256;
}

// ---- GEMM1: T = tanh(scl[row]*(hb @ W1^T) + b1) ----
__global__ __launch_bounds__(512, 2) void gemm_tanh(
    const unsigned short* __restrict__ A, const unsigned short* __restrict__ B,
    const float* __restrict__ bias, const float* __restrict__ scl,
    unsigned short* __restrict__ Cb) {
  __shared__ __align__(16) char smem[131072];
  const int tid = threadIdx.x, wave = tid >> 6, lane = tid & 63;
  const int quad = lane >> 4, l16 = lane & 15;
  const int wm = (wave >> 2) * 128, wn = (wave & 3) * 64;
  long m0, n0;
  xcd_tiles(m0, n0);
  floatx4 acc[8][4] = {};
  gemm_main(A, B, smem, tid, wm, wn, l16, quad, m0, n0, acc);
  __syncthreads();
  asm volatile("" ::: "memory");
  // epilogue: scale rows, bias, tanh -> bf16 into LDS, then coalesced stores
  short* Eh = (short*)smem;           // [256][256] bf16 = 128KB
  float sr[32];
#pragma unroll
  for (int i = 0; i < 8; ++i) {
    const float4 s4 = *(const float4*)(scl + m0 + wm + i * 16 + quad * 4);
    sr[i*4+0] = s4.x; sr[i*4+1] = s4.y; sr[i*4+2] = s4.z; sr[i*4+3] = s4.w;
  }
  float bcol[4];
#pragma unroll
  for (int j = 0; j < 4; ++j) bcol[j] = bias[n0 + wn + j * 16 + l16];
#pragma unroll
  for (int i = 0; i < 8; ++i) {
    const int row = wm + i * 16 + quad * 4;
#pragma unroll
    for (int j = 0; j < 4; ++j) {
      const int col = wn + j * 16 + l16;
#pragma unroll
      for (int r = 0; r < 4; ++r) {
        const float x = fmaf(sr[i*4+r], acc[i][j][r], bcol[j]);
        const float tt = 1.f - 2.f / (__expf(2.f * x) + 1.f);
        Eh[(row + r) * 256 + col] = (short)f2bf(tt);
      }
    }
  }
  __syncthreads();
#pragma unroll
  for (int s = 0; s < 16; ++s) {
    const int g = s * 512 + tid;
    const int row = g >> 5, c8 = (g & 31) * 8;
    *(short8*)(Cb + (m0 + row) * DIM + n0 + c8) = *(const short8*)(Eh + row * 256 + c8);
  }
}

// ---- GEMM2 + fused collapse update (uncapped h master; cf.x = ch*s folded) ----
template<int FULL>
__global__ __launch_bounds__(512, 2) void gemm_update(
    const unsigned short* __restrict__ A, const unsigned short* __restrict__ B,
    const float* __restrict__ bias, float* __restrict__ hf,
    unsigned short* __restrict__ hb, const float4* __restrict__ coef,
    const float* __restrict__ dirs) {
  __shared__ __align__(16) char smem[131072];
  const int tid = threadIdx.x, wave = tid >> 6, lane = tid & 63;
  const int quad = lane >> 4, l16 = lane & 15;
  const int wm = (wave >> 2) * 128, wn = (wave & 3) * 64;
  long m0, n0;
  xcd_tiles(m0, n0);
  floatx4 acc[8][4] = {};
  gemm_main(A, B, smem, tid, wm, wn, l16, quad, m0, n0, acc);
  asm volatile("" ::: "memory");
  // two j-half passes through LDS (fp32); coalesced float4 RMW of hf + hb mirror
  float* Ef = (float*)smem;           // [256][128] fp32 = 128KB
#pragma unroll
  for (int p = 0; p < 2; ++p) {
    __syncthreads();
#pragma unroll
    for (int i = 0; i < 8; ++i) {
      const int row = wm + i * 16 + quad * 4;
#pragma unroll
      for (int jj = 0; jj < 2; ++jj) {
        const int cc = (wn >> 1) + jj * 16 + l16;       // wave's 32-col stripe pair
#pragma unroll
        for (int r = 0; r < 4; ++r)
          Ef[(row + r) * 128 + cc] = acc[i][p * 2 + jj][r];
      }
    }
    __syncthreads();
#pragma unroll
    for (int s = 0; s < 16; ++s) {
      const int q = s * 512 + tid;
      const int row = q >> 5, c4 = (q & 31) * 4;
      const int col = ((c4 >> 5) * 64) + p * 32 + (c4 & 31);  // de-compact 32-stripes
      const long gr = m0 + row, gc = n0 + col;
      const float4 e  = *(const float4*)(Ef + row * 128 + c4);
      const float4 bv = *(const float4*)(bias + gc);
      const float4 de = *(const float4*)(dirs + gc);
      const float4 dc = *(const float4*)(dirs + DIM + gc);
      const float4 dn = *(const float4*)(dirs + 2*DIM + gc);
      const float4 cf = coef[gr];
      float4 hv;
      if (FULL) {
        hv = *(const float4*)(hf + gr * DIM + gc);
      } else {
        const short4v hs = *(const short4v*)(hb + gr * DIM + gc);
        hv.x = bf2f((unsigned short)hs.x); hv.y = bf2f((unsigned short)hs.y);
        hv.z = bf2f((unsigned short)hs.z); hv.w = bf2f((unsigned short)hs.w);
      }
      float4 v;
      v.x = e.x + bv.x; v.y = e.y + bv.y; v.z = e.z + bv.z; v.w = e.w + bv.w;
      v.x = fmaf(cf.x, hv.x, v.x); v.y = fmaf(cf.x, hv.y, v.y);
      v.z = fmaf(cf.x, hv.z, v.z); v.w = fmaf(cf.x, hv.w, v.w);
      v.x = fmaf(cf.y, de.x, v.x); v.y = fmaf(cf.y, de.y, v.y);
      v.z = fmaf(cf.y, de.z, v.z); v.w = fmaf(cf.y, de.w, v.w);
      v.x = fmaf(cf.z, dc.x, v.x); v.y = fmaf(cf.z, dc.y, v.y);
      v.z = fmaf(cf.z, dc.z, v.z); v.w = fmaf(cf.z, dc.w, v.w);
      v.x = fmaf(cf.w, dn.x, v.x); v.y = fmaf(cf.w, dn.y, v.y);
      v.z = fmaf(cf.w, dn.z, v.z); v.w = fmaf(cf.w, dn.w, v.w);
      if (FULL) *(float4*)(hf + gr * DIM + gc) = v;
      short4v ob;
      ob.x = (short)f2bf(v.x); ob.y = (short)f2bf(v.y);
      ob.z = (short)f2bf(v.z); ob.w = (short)f2bf(v.w);
      *(short4v*)(hb + gr * DIM + gc) = ob;
    }
  }
}

// ---- stats: read hb (uncapped), emit next-layer coef (cf.x=ch*s) + scl=s ----
__global__ __launch_bounds__(256) void k_stats(
    const unsigned short* __restrict__ hb, const float* __restrict__ dirs,
    float4* __restrict__ coef, float* __restrict__ scl) {
  const int tid = threadIdx.x, w = tid >> 6, lane = tid & 63;
  const long row = (long)blockIdx.x * 4 + w;
  const unsigned short* hr = hb + row * DIM;
  float s0 = 0.f, se = 0.f, sc = 0.f, sn = 0.f;
#pragma unroll
  for (int i = 0; i < 4; ++i) {
    const int o = i * 512 + lane * 8;
    const short8 h8 = *(const short8*)(hr + o);
    float h[8];
#pragma unroll
    for (int q = 0; q < 8; ++q) h[q] = bf2f((unsigned short)h8[q]);
    const float4 e0 = *(const float4*)(dirs + o),       e1 = *(const float4*)(dirs + o + 4);
    const float4 c0 = *(const float4*)(dirs + DIM + o), c1 = *(const float4*)(dirs + DIM + o + 4);
    const float4 n0v = *(const float4*)(dirs + 2*DIM + o), n1 = *(const float4*)(dirs + 2*DIM + o + 4);
    const float ee[8] = { e0.x,e0.y,e0.z,e0.w, e1.x,e1.y,e1.z,e1.w };
    const float ccv[8] = { c0.x,c0.y,c0.z,c0.w, c1.x,c1.y,c1.z,c1.w };
    const float nn[8] = { n0v.x,n0v.y,n0v.z,n0v.w, n1.x,n1.y,n1.z,n1.w };
#pragma unroll
    for (int q = 0; q < 8; ++q) {
      s0 = fmaf(h[q], h[q], s0);
      se = fmaf(h[q], ee[q], se);
      sc = fmaf(h[q], ccv[q], sc);
      sn = fmaf(h[q], nn[q], sn);
    }
  }
#pragma unroll
  for (int off = 32; off >= 1; off >>= 1) {
    s0 += __shfl_xor(s0, off); se += __shfl_xor(se, off);
    sc += __shfl_xor(sc, off); sn += __shfl_xor(sn, off);
  }
  if (lane == 0) {
    const float nrm = sqrtf(s0);
    const float s = (nrm > NCAP) ? (NCAP / (nrm + 1e-8f)) : 1.f;
    float4 cf = row_coef(s0 * s * s, se * s, sc * s, sn * s);
    cf.x *= s;                       // applied to UNCAPPED h master
    coef[row] = cf;
    scl[row] = s;
  }
}

// ---- finish: norm-cap final h_pre, write d_out (dtype by flag) ----
template<int FULL>
__global__ __launch_bounds__(256) void k_finish(
    const float* __restrict__ hf, const unsigned short* __restrict__ hb,
    const int* __restrict__ flag, void* __restrict__ dout) {
  const int tid = threadIdx.x, w = tid >> 6, lane = tid & 63;
  const long row = (long)blockIdx.x * 4 + w;
  float4 hv[8];
  float s0 = 0.f;
#pragma unroll
  for (int i = 0; i < 8; ++i) {
    const int o = i * 256 + lane * 4;
    if (FULL) {
      hv[i] = *(const float4*)(hf + row * DIM + o);
    } else {
      const short4v hs = *(const short4v*)(hb + row * DIM + o);
      hv[i].x = bf2f((unsigned short)hs.x); hv[i].y = bf2f((unsigned short)hs.y);
      hv[i].z = bf2f((unsigned short)hs.z); hv[i].w = bf2f((unsigned short)hs.w);
    }
    s0 = fmaf(hv[i].x,hv[i].x,fmaf(hv[i].y,hv[i].y,fmaf(hv[i].z,hv[i].z,fmaf(hv[i].w,hv[i].w,s0))));
  }
#pragma unroll
  for (int off = 32; off >= 1; off >>= 1) s0 += __shfl_xor(s0, off);
  const float nrm = sqrtf(s0);
  const float s = (nrm > NCAP) ? (NCAP / (nrm + 1e-8f)) : 1.f;
  const int isf32 = *flag;
#pragma unroll
  for (int i = 0; i < 8; ++i) {
    const int o = i * 256 + lane * 4;
    float4 v;
    v.x = hv[i].x * s; v.y = hv[i].y * s; v.z = hv[i].z * s; v.w = hv[i].w * s;
    if (isf32) {
      *((float4*)dout + (row * DIM + o) / 4) = v;
    } else {
      short4v ob;
      ob.x = (short)f2bf(v.x); ob.y = (short)f2bf(v.y);
      ob.z = (short)f2bf(v.z); ob.w = (short)f2bf(v.w);
      *((short4v*)dout + (row * DIM + o) / 4) = ob;
    }
  }
}

extern "C" void kernel_launch(void* const* d_in, const int* in_sizes, int n_in,
                              void* d_out, int out_size, void* d_ws, size_t ws_size,
                              hipStream_t stream) {
  const void* h0  = d_in[0];
  const void* A_e = d_in[1];
  const void* A_c = d_in[2];
  const void* A_n = d_in[3];
  const void* W1  = d_in[4];
  const void* b1  = d_in[5];
  const void* W2  = d_in[6];
  const void* b2  = d_in[7];

  char* base = (char*)d_ws;
  size_t off = 0;
  auto take = [&](size_t n) -> char* {
    char* p = base + off; off += (n + 255) & ~(size_t)255; return p;
  };
  int*            flag = (int*)take(4);
  float*          dirs = (float*)take(3 * DIM * 4);
  float*          b1f  = (float*)take(DIM * 4);
  float*          b2f  = (float*)take(DIM * 4);
  float4*         coef = (float4*)take((size_t)BATCH * 16);
  float*          scl  = (float*)take((size_t)BATCH * 4);
  unsigned short* W1b  = (unsigned short*)take((size_t)DIM * DIM * 2);
  unsigned short* W2b  = (unsigned short*)take((size_t)DIM * DIM * 2);
  unsigned short* T    = (unsigned short*)take((size_t)BATCH * DIM * 2);
  unsigned short* hb   = (unsigned short*)take((size_t)BATCH * DIM * 2);
  float*          hf   = (float*)take((size_t)BATCH * DIM * 4);   // LAST (fallback drops it)
  const size_t need_full = off;
  const bool full = (ws_size >= need_full);

  k_detect<<<1, 64, 0, stream>>>((const unsigned short*)h0, flag);
  k_prep_w<<<dim3(4096, 2), 256, 0, stream>>>(W1, W2, flag, W1b, W2b);
  k_prep_small<<<1, 256, 0, stream>>>(b1, b2, A_e, A_c, A_n, flag, b1f, b2f, dirs);

  const dim3 gg(DIM / 256, BATCH / 256);
  if (full) {
    k_boot<1><<<BATCH, 256, 0, stream>>>(h0, flag, dirs, hf, hb, coef, scl);
    for (int L = 0; L < 4; ++L) {
      gemm_tanh<<<gg, 512, 0, stream>>>(hb, W1b, b1f, scl, T);
      gemm_update<1><<<gg, 512, 0, stream>>>(T, W2b, b2f, hf, hb, coef, dirs);
      if (L < 3) k_stats<<<BATCH/4, 256, 0, stream>>>(hb, dirs, coef, scl);
    }
    k_finish<1><<<BATCH/4, 256, 0, stream>>>(hf, hb, flag, d_out);
  } else {
    k_boot<0><<<BATCH, 256, 0, stream>>>(h0, flag, dirs, nullptr, hb, coef, scl);
    for (int L = 0; L < 4; ++L) {
      gemm_tanh<<<gg, 512, 0, stream>>>(hb, W1b, b1f, scl, T);
      gemm_update<0><<<gg, 512, 0, stream>>>(T, W2b, b2f, nullptr, hb, coef, dirs);
      if (L < 3) k_stats<<<BATCH/4, 256, 0, stream>>>(hb, dirs, coef, scl);
    }
    k_finish<0><<<BATCH/4, 256, 0, stream>>>(nullptr, hb, flag, d_out);
  }
}

// Round 4
// 1852.437 us; speedup vs baseline: 1.0861x; 1.0063x over previous
//
#include <hip/hip_runtime.h>
#include <stdint.h>

#define DIM      2048
#define BATCH    16384
#define S_E      0.1f
#define S_C      0.1f
#define S_N      0.05f
#define DIVC     0.38f
#define NCAP     10.0f

typedef __attribute__((ext_vector_type(4))) float floatx4;
typedef __attribute__((ext_vector_type(8))) short short8;
typedef __attribute__((ext_vector_type(4))) short short4v;

__device__ __forceinline__ float bf2f(unsigned short u) {
  union { float f; unsigned v; } x; x.v = ((unsigned)u) << 16; return x.f;
}
__device__ __forceinline__ unsigned short f2bf(float f) {
  union { float f; unsigned v; } x; x.f = f;
  unsigned r = x.v + 0x7FFFu + ((x.v >> 16) & 1u);   // RNE
  return (unsigned short)(r >> 16);
}

__device__ __forceinline__ void gload_lds16(const void* g, void* l) {
  __builtin_amdgcn_global_load_lds((const __attribute__((address_space(1))) void*)g,
                                   (__attribute__((address_space(3))) void*)l,
                                   16, 0, 0);
}

// ---- dtype detector: flag=1 -> fp32 inputs, flag=0 -> bf16 ----
__global__ void k_detect(const unsigned short* __restrict__ h0u, int* __restrict__ flag) {
  const int lane = threadIdx.x;
  int bad = 0;
#pragma unroll
  for (int i = 0; i < 32; ++i) {
    const unsigned u = h0u[lane + i * 64];
    const unsigned e = (u >> 7) & 0xFF;
    bad |= (e >= 0x84);
  }
  const unsigned long long m = __ballot(bad);
  if (lane == 0) *flag = (m != 0ull) ? 1 : 0;
}

__global__ __launch_bounds__(256) void k_prep_w(
    const void* __restrict__ w1r, const void* __restrict__ w2r,
    const int* __restrict__ flag,
    unsigned short* __restrict__ W1b, unsigned short* __restrict__ W2b) {
  const void* src = blockIdx.y ? w2r : w1r;
  unsigned short* dst = blockIdx.y ? W2b : W1b;
  const long i4 = (long)blockIdx.x * 256 + threadIdx.x;
  if (*flag) {
    const float4 v = ((const float4*)src)[i4];
    short4v o;
    o.x = (short)f2bf(v.x); o.y = (short)f2bf(v.y);
    o.z = (short)f2bf(v.z); o.w = (short)f2bf(v.w);
    ((short4v*)dst)[i4] = o;
  } else {
    ((short4v*)dst)[i4] = ((const short4v*)src)[i4];
  }
}

__global__ __launch_bounds__(256) void k_prep_small(
    const void* __restrict__ b1r, const void* __restrict__ b2r,
    const void* __restrict__ a0r, const void* __restrict__ a1r,
    const void* __restrict__ a2r, const int* __restrict__ flag,
    float* __restrict__ b1f, float* __restrict__ b2f, float* __restrict__ dirs) {
  __shared__ float red[4];
  const int tid = threadIdx.x, wave = tid >> 6, lane = tid & 63;
  const int isf32 = *flag;
#pragma unroll
  for (int i = 0; i < 8; ++i) {
    const int idx = i * 256 + tid;
    b1f[idx] = isf32 ? ((const float*)b1r)[idx] : bf2f(((const unsigned short*)b1r)[idx]);
    b2f[idx] = isf32 ? ((const float*)b2r)[idx] : bf2f(((const unsigned short*)b2r)[idx]);
  }
  const void* ar[3] = { a0r, a1r, a2r };
  for (int a = 0; a < 3; ++a) {
    float v[8]; float s = 0.f;
#pragma unroll
    for (int i = 0; i < 8; ++i) {
      const int idx = i * 256 + tid;
      v[i] = isf32 ? ((const float*)ar[a])[idx] : bf2f(((const unsigned short*)ar[a])[idx]);
      s = fmaf(v[i], v[i], s);
    }
#pragma unroll
    for (int off = 32; off >= 1; off >>= 1) s += __shfl_xor(s, off);
    if (lane == 0) red[wave] = s;
    __syncthreads();
    const float S = red[0] + red[1] + red[2] + red[3];
    const float inv = 1.f / fmaxf(sqrtf(S), 1e-12f);
#pragma unroll
    for (int i = 0; i < 8; ++i) dirs[a * DIM + i * 256 + tid] = v[i] * inv;
    __syncthreads();
  }
}

// coefs from CAPPED row stats (unit dirs: ||h-d||^2 = S0 - 2 h.d + 1)
__device__ __forceinline__ float4 row_coef(float S0, float Se, float Sc, float Sn) {
  const float Li = 1.f / fmaxf(sqrtf(S0), 1e-12f);
  const float ce = S_E * (DIVC - Se * Li) / fmaxf(sqrtf(fmaxf(S0 - 2.f * Se + 1.f, 0.f)), 1e-12f);
  const float cc = S_C * (DIVC - Sc * Li) / fmaxf(sqrtf(fmaxf(S0 - 2.f * Sc + 1.f, 0.f)), 1e-12f);
  const float cn = S_N * (DIVC - Sn * Li) / fmaxf(sqrtf(fmaxf(S0 - 2.f * Sn + 1.f, 0.f)), 1e-12f);
  float4 c; c.x = 1.f - (ce + cc + cn); c.y = ce; c.z = cc; c.w = cn; return c;
}

// ---- boot: h0 -> hf (FULL) + hb + coef (s=1) + scl=1 ----
template<int FULL>
__global__ __launch_bounds__(256) void k_boot(
    const void* __restrict__ h0raw, const int* __restrict__ flag,
    const float* __restrict__ dirs, float* __restrict__ hf,
    unsigned short* __restrict__ hb, float4* __restrict__ coef,
    float* __restrict__ scl) {
  __shared__ float red[16];
  const long row = blockIdx.x;
  const int tid = threadIdx.x, wave = tid >> 6, lane = tid & 63;
  const int isf32 = *flag;
  float h[8];
  float s0 = 0.f, se = 0.f, sc = 0.f, sn = 0.f;
#pragma unroll
  for (int i = 0; i < 2; ++i) {
    const int c4 = i * 256 + tid;
    float4 hv;
    if (isf32) {
      hv = ((const float4*)h0raw + row * (DIM/4))[c4];
    } else {
      const short4v hs = ((const short4v*)h0raw + row * (DIM/4))[c4];
      hv.x = bf2f((unsigned short)hs.x); hv.y = bf2f((unsigned short)hs.y);
      hv.z = bf2f((unsigned short)hs.z); hv.w = bf2f((unsigned short)hs.w);
    }
    const float4 ev = ((const float4*)dirs)[c4];
    const float4 cv = ((const float4*)(dirs + DIM))[c4];
    const float4 nv = ((const float4*)(dirs + 2*DIM))[c4];
    h[i*4+0]=hv.x; h[i*4+1]=hv.y; h[i*4+2]=hv.z; h[i*4+3]=hv.w;
    s0 = fmaf(hv.x,hv.x,fmaf(hv.y,hv.y,fmaf(hv.z,hv.z,fmaf(hv.w,hv.w,s0))));
    se = fmaf(hv.x,ev.x,fmaf(hv.y,ev.y,fmaf(hv.z,ev.z,fmaf(hv.w,ev.w,se))));
    sc = fmaf(hv.x,cv.x,fmaf(hv.y,cv.y,fmaf(hv.z,cv.z,fmaf(hv.w,cv.w,sc))));
    sn = fmaf(hv.x,nv.x,fmaf(hv.y,nv.y,fmaf(hv.z,nv.z,fmaf(hv.w,nv.w,sn))));
  }
#pragma unroll
  for (int off = 32; off >= 1; off >>= 1) {
    s0 += __shfl_xor(s0, off); se += __shfl_xor(se, off);
    sc += __shfl_xor(sc, off); sn += __shfl_xor(sn, off);
  }
  if (lane == 0) { red[wave*4+0]=s0; red[wave*4+1]=se; red[wave*4+2]=sc; red[wave*4+3]=sn; }
  __syncthreads();
  if (tid == 0) {
    const float S0 = red[0]+red[4]+red[8]+red[12];
    const float Se = red[1]+red[5]+red[9]+red[13];
    const float Sc = red[2]+red[6]+red[10]+red[14];
    const float Sn = red[3]+red[7]+red[11]+red[15];
    coef[row] = row_coef(S0, Se, Sc, Sn);   // h0 is not pre-capped; s=1
    scl[row] = 1.f;
  }
#pragma unroll
  for (int i = 0; i < 2; ++i) {
    const int c4 = i * 256 + tid;
    if (FULL) {
      float4 o; o.x=h[i*4+0]; o.y=h[i*4+1]; o.z=h[i*4+2]; o.w=h[i*4+3];
      ((float4*)hf + row * (DIM/4))[c4] = o;
    }
    short4v ob;
    ob.x=(short)f2bf(h[i*4+0]); ob.y=(short)f2bf(h[i*4+1]);
    ob.z=(short)f2bf(h[i*4+2]); ob.w=(short)f2bf(h[i*4+3]);
    ((short4v*)hb + row * (DIM/4))[c4] = ob;
  }
}

// ============================================================================
// 256x256-tile GEMM core — m201-style 8-phase schedule (T3+T4+T2+T5).
//
// - 512 threads = 8 waves (2M x 4N); wave owns 128x64 C.  BK=64.
// - LDS 128KB: A0[0,32K) B0[32K,64K) A1[64K,96K) B1[96K,128K); [256][64] bf16,
//   128B rows, chunk-swizzled: stored 16B-chunk cs of row r holds global chunk
//   cs ^ (r&7).  gload_lds dest linear; swizzle via pre-swizzled global col
//   ((tid&7)^((tid>>3)&7)); reads XOR (l16&7).  2 lanes/bank per quarter = free.
// - Iter = 2 K-tiles (t even in buf0, t+1 in buf1), 8 phases, each:
//   {ds_reads ; 2 gload_lds ; barrier ; lgkmcnt(0) ; setprio1 ; 16 MFMA
//    (one C-quadrant x K=64) ; setprio0 ; [vmcnt(4) @P4/P8] ; barrier}.
// - NOTE: waitcnt asm must carry NO "memory" clobber — a memory-clobbered
//   INLINEASM is mayLoad/mayStore, and SIInsertWaitcnts conservatively emits
//   s_waitcnt vmcnt(0) lgkmcnt(0) before it, draining the staging queue every
//   phase (observed R2/R3: both schedules pinned at identical 258us, 22%
//   MfmaUtil).  Ordering is pinned by sched_barrier(0) + barrier/setprio.
// - Quadrant order per tile: (ih,jh) = (0,0),(1,0),(0,1),(1,1); A-halves kept
//   in regs (a0,a1) so A-LDS dead after P2, B-LDS dead after P3.
// - Stage slots (targets provably dead, vmcnt uniform 2/phase):
//   P1,P2: B(t+1)->B1   P3,P4: A(t+2)->A0   P5,P6: B(t+2)->B0
//   P7,P8: A(t+3)->A1.  vmcnt(4) at P4 (t+1 landed) and P8 (t+2 landed).
// - Tail: stage source k clamped to tile 31 (dest regions dead; data unused).
// ============================================================================

__device__ __forceinline__ void gemm_main(
    const unsigned short* __restrict__ A, const unsigned short* __restrict__ B,
    char* __restrict__ smem, const int tid, const int wm, const int wn,
    const int l16, const int quad, const long m0, const long n0,
    floatx4 (&acc)[8][4]) {
  const int s3 = l16 & 7;
  const int csw = ((tid & 7) ^ ((tid >> 3) & 7)) * 8;
  const unsigned short* Ag = A + (m0 + (tid >> 3)) * DIM + csw;
  const unsigned short* Bg = B + (n0 + (tid >> 3)) * DIM + csw;
  short* lds = (short*)smem;
  const int ao0 = (wm + l16) * 64 + ((quad ^ s3)) * 8;
  const int ao1 = (wm + l16) * 64 + (((quad + 4) ^ s3)) * 8;
  const int bo0 = (wn + l16) * 64 + ((quad ^ s3)) * 8;
  const int bo1 = (wn + l16) * 64 + (((quad + 4) ^ s3)) * 8;

#define STAGE_A(dbuf, ts, h) { \
    const unsigned short* s_ = Ag + (size_t)((h) * 128) * DIM + (ts) * 64; \
    char* d_ = smem + (dbuf) * 65536 + (h) * 16384 + tid * 16; \
    gload_lds16(s_, d_); gload_lds16(s_ + (size_t)64 * DIM, d_ + 8192); }
#define STAGE_B(dbuf, ts, h) { \
    const unsigned short* s_ = Bg + (size_t)((h) * 128) * DIM + (ts) * 64; \
    char* d_ = smem + (dbuf) * 65536 + 32768 + (h) * 16384 + tid * 16; \
    gload_lds16(s_, d_); gload_lds16(s_ + (size_t)64 * DIM, d_ + 8192); }
#define RD_A(dst, bufo, ih) { \
    _Pragma("unroll") for (int i_ = 0; i_ < 4; ++i_) { \
      dst[i_][0] = *(const short8*)(lds + (bufo) + (ih) * 4096 + i_ * 1024 + ao0); \
      dst[i_][1] = *(const short8*)(lds + (bufo) + (ih) * 4096 + i_ * 1024 + ao1); } }
#define RD_B(bufo, jh) { \
    _Pragma("unroll") for (int j_ = 0; j_ < 2; ++j_) { \
      bR[j_][0] = *(const short8*)(lds + (bufo) + 16384 + (jh) * 2048 + j_ * 1024 + bo0); \
      bR[j_][1] = *(const short8*)(lds + (bufo) + 16384 + (jh) * 2048 + j_ * 1024 + bo1); } }
#define MF(ih, jh, aR) \
    __builtin_amdgcn_sched_barrier(0); \
    __builtin_amdgcn_s_barrier(); \
    asm volatile("s_waitcnt lgkmcnt(0)"); \
    __builtin_amdgcn_sched_barrier(0); \
    __builtin_amdgcn_s_setprio(1); \
    _Pragma("unroll") for (int i_ = 0; i_ < 4; ++i_) \
    _Pragma("unroll") for (int j_ = 0; j_ < 2; ++j_) { \
      acc[(ih)*4+i_][(jh)*2+j_] = __builtin_amdgcn_mfma_f32_16x16x32_bf16(aR[i_][0], bR[j_][0], acc[(ih)*4+i_][(jh)*2+j_], 0, 0, 0); \
      acc[(ih)*4+i_][(jh)*2+j_] = __builtin_amdgcn_mfma_f32_16x16x32_bf16(aR[i_][1], bR[j_][1], acc[(ih)*4+i_][(jh)*2+j_], 0, 0, 0); } \
    __builtin_amdgcn_s_setprio(0); \
    __builtin_amdgcn_sched_barrier(0);
#define ENDPH    { __builtin_amdgcn_s_barrier(); __builtin_amdgcn_sched_barrier(0); }
#define ENDPH_VM { asm volatile("s_waitcnt vmcnt(4)"); \
                   __builtin_amdgcn_sched_barrier(0); \
                   __builtin_amdgcn_s_barrier(); __builtin_amdgcn_sched_barrier(0); }

  short8 a0[4][2], a1[4][2], bR[2][2];
  // prologue: A(0)->A0, B(0)->B0, A(1)->A1 (12 loads); wait tile0 (leave A(1))
  STAGE_A(0, 0, 0); STAGE_A(0, 0, 1);
  STAGE_B(0, 0, 0); STAGE_B(0, 0, 1);
  STAGE_A(1, 1, 0); STAGE_A(1, 1, 1);
  asm volatile("s_waitcnt vmcnt(4)");
  __builtin_amdgcn_sched_barrier(0);
  __builtin_amdgcn_s_barrier();
  __builtin_amdgcn_sched_barrier(0);

#pragma unroll 1
  for (int it = 0; it < DIM / 128; ++it) {
    const int t = it * 2;
    const int t2 = (t + 2 < 31) ? (t + 2) : 31;
    const int t3 = (t + 3 < 31) ? (t + 3) : 31;
    // P1: Q(0,0) tile t
    RD_A(a0, 0, 0); RD_B(0, 0); STAGE_B(1, t + 1, 0);
    MF(0, 0, a0) ENDPH
    // P2: Q(1,0)
    RD_A(a1, 0, 1); STAGE_B(1, t + 1, 1);
    MF(1, 0, a1) ENDPH
    // P3: Q(0,1)
    RD_B(0, 1); STAGE_A(0, t2, 0);
    MF(0, 1, a0) ENDPH
    // P4: Q(1,1)  [boundary: t+1 landed]
    STAGE_A(0, t2, 1);
    MF(1, 1, a1) ENDPH_VM
    // P5: Q(0,0) tile t+1
    RD_A(a0, 32768, 0); RD_B(32768, 0); STAGE_B(0, t2, 0);
    MF(0, 0, a0) ENDPH
    // P6: Q(1,0)
    RD_A(a1, 32768, 1); STAGE_B(0, t2, 1);
    MF(1, 0, a1) ENDPH
    // P7: Q(0,1)
    RD_B(32768, 1); STAGE_A(1, t3, 0);
    MF(0, 1, a0) ENDPH
    // P8: Q(1,1)  [boundary: t+2 landed]
    STAGE_A(1, t3, 1);
    MF(1, 1, a1) ENDPH_VM
  }
#undef STAGE_A
#undef STAGE_B
#undef RD_A
#undef RD_B
#undef MF
#undef ENDPH
#undef ENDPH_VM
}

// XCD-aware bijective block swizzle: 512 wg, 8 XCDs, n-tile fastest per XCD
__device__ __forceinline__ void xcd_tiles(long& m0, long& n0) {
  const int b = blockIdx.y * (DIM / 256) + blockIdx.x;     // 0..511
  const int swz = (b & 7) * ((BATCH / 256) * (DIM / 256) / 8) + (b >> 3);
  m0 = (long)(swz >> 3) * 256;                             // 8 n-tiles
  n0 = (long)(swz & 7) * 256;
}

// ---- GEMM1: T = tanh(scl[row]*(hb @ W1^T) + b1) ----
__global__ __launch_bounds__(512, 2) void gemm_tanh(
    const unsigned short* __restrict__ A, const unsigned short* __restrict__ B,
    const float* __restrict__ bias, const float* __restrict__ scl,
    unsigned short* __restrict__ Cb) {
  __shared__ __align__(16) char smem[131072];
  const int tid = threadIdx.x, wave = tid >> 6, lane = tid & 63;
  const int quad = lane >> 4, l16 = lane & 15;
  const int wm = (wave >> 2) * 128, wn = (wave & 3) * 64;
  long m0, n0;
  xcd_tiles(m0, n0);
  floatx4 acc[8][4] = {};
  gemm_main(A, B, smem, tid, wm, wn, l16, quad, m0, n0, acc);
  __syncthreads();
  asm volatile("" ::: "memory");
  // epilogue: scale rows, bias, tanh -> bf16 into LDS, then coalesced stores
  short* Eh = (short*)smem;           // [256][256] bf16 = 128KB
  float sr[32];
#pragma unroll
  for (int i = 0; i < 8; ++i) {
    const float4 s4 = *(const float4*)(scl + m0 + wm + i * 16 + quad * 4);
    sr[i*4+0] = s4.x; sr[i*4+1] = s4.y; sr[i*4+2] = s4.z; sr[i*4+3] = s4.w;
  }
  float bcol[4];
#pragma unroll
  for (int j = 0; j < 4; ++j) bcol[j] = bias[n0 + wn + j * 16 + l16];
#pragma unroll
  for (int i = 0; i < 8; ++i) {
    const int row = wm + i * 16 + quad * 4;
#pragma unroll
    for (int j = 0; j < 4; ++j) {
      const int col = wn + j * 16 + l16;
#pragma unroll
      for (int r = 0; r < 4; ++r) {
        const float x = fmaf(sr[i*4+r], acc[i][j][r], bcol[j]);
        const float tt = 1.f - 2.f / (__expf(2.f * x) + 1.f);
        Eh[(row + r) * 256 + col] = (short)f2bf(tt);
      }
    }
  }
  __syncthreads();
#pragma unroll
  for (int s = 0; s < 16; ++s) {
    const int g = s * 512 + tid;
    const int row = g >> 5, c8 = (g & 31) * 8;
    *(short8*)(Cb + (m0 + row) * DIM + n0 + c8) = *(const short8*)(Eh + row * 256 + c8);
  }
}

// ---- GEMM2 + fused collapse update (uncapped h master; cf.x = ch*s folded) ----
template<int FULL>
__global__ __launch_bounds__(512, 2) void gemm_update(
    const unsigned short* __restrict__ A, const unsigned short* __restrict__ B,
    const float* __restrict__ bias, float* __restrict__ hf,
    unsigned short* __restrict__ hb, const float4* __restrict__ coef,
    const float* __restrict__ dirs) {
  __shared__ __align__(16) char smem[131072];
  const int tid = threadIdx.x, wave = tid >> 6, lane = tid & 63;
  const int quad = lane >> 4, l16 = lane & 15;
  const int wm = (wave >> 2) * 128, wn = (wave & 3) * 64;
  long m0, n0;
  xcd_tiles(m0, n0);
  floatx4 acc[8][4] = {};
  gemm_main(A, B, smem, tid, wm, wn, l16, quad, m0, n0, acc);
  asm volatile("" ::: "memory");
  // two j-half passes through LDS (fp32); coalesced float4 RMW of hf + hb mirror
  float* Ef = (float*)smem;           // [256][128] fp32 = 128KB
#pragma unroll
  for (int p = 0; p < 2; ++p) {
    __syncthreads();
#pragma unroll
    for (int i = 0; i < 8; ++i) {
      const int row = wm + i * 16 + quad * 4;
#pragma unroll
      for (int jj = 0; jj < 2; ++jj) {
        const int cc = (wn >> 1) + jj * 16 + l16;       // wave's 32-col stripe pair
#pragma unroll
        for (int r = 0; r < 4; ++r)
          Ef[(row + r) * 128 + cc] = acc[i][p * 2 + jj][r];
      }
    }
    __syncthreads();
#pragma unroll
    for (int s = 0; s < 16; ++s) {
      const int q = s * 512 + tid;
      const int row = q >> 5, c4 = (q & 31) * 4;
      const int col = ((c4 >> 5) * 64) + p * 32 + (c4 & 31);  // de-compact 32-stripes
      const long gr = m0 + row, gc = n0 + col;
      const float4 e  = *(const float4*)(Ef + row * 128 + c4);
      const float4 bv = *(const float4*)(bias + gc);
      const float4 de = *(const float4*)(dirs + gc);
      const float4 dc = *(const float4*)(dirs + DIM + gc);
      const float4 dn = *(const float4*)(dirs + 2*DIM + gc);
      const float4 cf = coef[gr];
      float4 hv;
      if (FULL) {
        hv = *(const float4*)(hf + gr * DIM + gc);
      } else {
        const short4v hs = *(const short4v*)(hb + gr * DIM + gc);
        hv.x = bf2f((unsigned short)hs.x); hv.y = bf2f((unsigned short)hs.y);
        hv.z = bf2f((unsigned short)hs.z); hv.w = bf2f((unsigned short)hs.w);
      }
      float4 v;
      v.x = e.x + bv.x; v.y = e.y + bv.y; v.z = e.z + bv.z; v.w = e.w + bv.w;
      v.x = fmaf(cf.x, hv.x, v.x); v.y = fmaf(cf.x, hv.y, v.y);
      v.z = fmaf(cf.x, hv.z, v.z); v.w = fmaf(cf.x, hv.w, v.w);
      v.x = fmaf(cf.y, de.x, v.x); v.y = fmaf(cf.y, de.y, v.y);
      v.z = fmaf(cf.y, de.z, v.z); v.w = fmaf(cf.y, de.w, v.w);
      v.x = fmaf(cf.z, dc.x, v.x); v.y = fmaf(cf.z, dc.y, v.y);
      v.z = fmaf(cf.z, dc.z, v.z); v.w = fmaf(cf.z, dc.w, v.w);
      v.x = fmaf(cf.w, dn.x, v.x); v.y = fmaf(cf.w, dn.y, v.y);
      v.z = fmaf(cf.w, dn.z, v.z); v.w = fmaf(cf.w, dn.w, v.w);
      if (FULL) *(float4*)(hf + gr * DIM + gc) = v;
      short4v ob;
      ob.x = (short)f2bf(v.x); ob.y = (short)f2bf(v.y);
      ob.z = (short)f2bf(v.z); ob.w = (short)f2bf(v.w);
      *(short4v*)(hb + gr * DIM + gc) = ob;
    }
  }
}

// ---- stats: read hb (uncapped), emit next-layer coef (cf.x=ch*s) + scl=s ----
__global__ __launch_bounds__(256) void k_stats(
    const unsigned short* __restrict__ hb, const float* __restrict__ dirs,
    float4* __restrict__ coef, float* __restrict__ scl) {
  const int tid = threadIdx.x, w = tid >> 6, lane = tid & 63;
  const long row = (long)blockIdx.x * 4 + w;
  const unsigned short* hr = hb + row * DIM;
  float s0 = 0.f, se = 0.f, sc = 0.f, sn = 0.f;
#pragma unroll
  for (int i = 0; i < 4; ++i) {
    const int o = i * 512 + lane * 8;
    const short8 h8 = *(const short8*)(hr + o);
    float h[8];
#pragma unroll
    for (int q = 0; q < 8; ++q) h[q] = bf2f((unsigned short)h8[q]);
    const float4 e0 = *(const float4*)(dirs + o),       e1 = *(const float4*)(dirs + o + 4);
    const float4 c0 = *(const float4*)(dirs + DIM + o), c1 = *(const float4*)(dirs + DIM + o + 4);
    const float4 n0v = *(const float4*)(dirs + 2*DIM + o), n1 = *(const float4*)(dirs + 2*DIM + o + 4);
    const float ee[8] = { e0.x,e0.y,e0.z,e0.w, e1.x,e1.y,e1.z,e1.w };
    const float ccv[8] = { c0.x,c0.y,c0.z,c0.w, c1.x,c1.y,c1.z,c1.w };
    const float nn[8] = { n0v.x,n0v.y,n0v.z,n0v.w, n1.x,n1.y,n1.z,n1.w };
#pragma unroll
    for (int q = 0; q < 8; ++q) {
      s0 = fmaf(h[q], h[q], s0);
      se = fmaf(h[q], ee[q], se);
      sc = fmaf(h[q], ccv[q], sc);
      sn = fmaf(h[q], nn[q], sn);
    }
  }
#pragma unroll
  for (int off = 32; off >= 1; off >>= 1) {
    s0 += __shfl_xor(s0, off); se += __shfl_xor(se, off);
    sc += __shfl_xor(sc, off); sn += __shfl_xor(sn, off);
  }
  if (lane == 0) {
    const float nrm = sqrtf(s0);
    const float s = (nrm > NCAP) ? (NCAP / (nrm + 1e-8f)) : 1.f;
    float4 cf = row_coef(s0 * s * s, se * s, sc * s, sn * s);
    cf.x *= s;                       // applied to UNCAPPED h master
    coef[row] = cf;
    scl[row] = s;
  }
}

// ---- finish: norm-cap final h_pre, write d_out (dtype by flag) ----
template<int FULL>
__global__ __launch_bounds__(256) void k_finish(
    const float* __restrict__ hf, const unsigned short* __restrict__ hb,
    const int* __restrict__ flag, void* __restrict__ dout) {
  const int tid = threadIdx.x, w = tid >> 6, lane = tid & 63;
  const long row = (long)blockIdx.x * 4 + w;
  float4 hv[8];
  float s0 = 0.f;
#pragma unroll
  for (int i = 0; i < 8; ++i) {
    const int o = i * 256 + lane * 4;
    if (FULL) {
      hv[i] = *(const float4*)(hf + row * DIM + o);
    } else {
      const short4v hs = *(const short4v*)(hb + row * DIM + o);
      hv[i].x = bf2f((unsigned short)hs.x); hv[i].y = bf2f((unsigned short)hs.y);
      hv[i].z = bf2f((unsigned short)hs.z); hv[i].w = bf2f((unsigned short)hs.w);
    }
    s0 = fmaf(hv[i].x,hv[i].x,fmaf(hv[i].y,hv[i].y,fmaf(hv[i].z,hv[i].z,fmaf(hv[i].w,hv[i].w,s0))));
  }
#pragma unroll
  for (int off = 32; off >= 1; off >>= 1) s0 += __shfl_xor(s0, off);
  const float nrm = sqrtf(s0);
  const float s = (nrm > NCAP) ? (NCAP / (nrm + 1e-8f)) : 1.f;
  const int isf32 = *flag;
#pragma unroll
  for (int i = 0; i < 8; ++i) {
    const int o = i * 256 + lane * 4;
    float4 v;
    v.x = hv[i].x * s; v.y = hv[i].y * s; v.z = hv[i].z * s; v.w = hv[i].w * s;
    if (isf32) {
      *((float4*)dout + (row * DIM + o) / 4) = v;
    } else {
      short4v ob;
      ob.x = (short)f2bf(v.x); ob.y = (short)f2bf(v.y);
      ob.z = (short)f2bf(v.z); ob.w = (short)f2bf(v.w);
      *((short4v*)dout + (row * DIM + o) / 4) = ob;
    }
  }
}

extern "C" void kernel_launch(void* const* d_in, const int* in_sizes, int n_in,
                              void* d_out, int out_size, void* d_ws, size_t ws_size,
                              hipStream_t stream) {
  const void* h0  = d_in[0];
  const void* A_e = d_in[1];
  const void* A_c = d_in[2];
  const void* A_n = d_in[3];
  const void* W1  = d_in[4];
  const void* b1  = d_in[5];
  const void* W2  = d_in[6];
  const void* b2  = d_in[7];

  char* base = (char*)d_ws;
  size_t off = 0;
  auto take = [&](size_t n) -> char* {
    char* p = base + off; off += (n + 255) & ~(size_t)255; return p;
  };
  int*            flag = (int*)take(4);
  float*          dirs = (float*)take(3 * DIM * 4);
  float*          b1f  = (float*)take(DIM * 4);
  float*          b2f  = (float*)take(DIM * 4);
  float4*         coef = (float4*)take((size_t)BATCH * 16);
  float*          scl  = (float*)take((size_t)BATCH * 4);
  unsigned short* W1b  = (unsigned short*)take((size_t)DIM * DIM * 2);
  unsigned short* W2b  = (unsigned short*)take((size_t)DIM * DIM * 2);
  unsigned short* T    = (unsigned short*)take((size_t)BATCH * DIM * 2);
  unsigned short* hb   = (unsigned short*)take((size_t)BATCH * DIM * 2);
  float*          hf   = (float*)take((size_t)BATCH * DIM * 4);   // LAST (fallback drops it)
  const size_t need_full = off;
  const bool full = (ws_size >= need_full);

  k_detect<<<1, 64, 0, stream>>>((const unsigned short*)h0, flag);
  k_prep_w<<<dim3(4096, 2), 256, 0, stream>>>(W1, W2, flag, W1b, W2b);
  k_prep_small<<<1, 256, 0, stream>>>(b1, b2, A_e, A_c, A_n, flag, b1f, b2f, dirs);

  const dim3 gg(DIM / 256, BATCH / 256);
  if (full) {
    k_boot<1><<<BATCH, 256, 0, stream>>>(h0, flag, dirs, hf, hb, coef, scl);
    for (int L = 0; L < 4; ++L) {
      gemm_tanh<<<gg, 512, 0, stream>>>(hb, W1b, b1f, scl, T);
      gemm_update<1><<<gg, 512, 0, stream>>>(T, W2b, b2f, hf, hb, coef, dirs);
      if (L < 3) k_stats<<<BATCH/4, 256, 0, stream>>>(hb, dirs, coef, scl);
    }
    k_finish<1><<<BATCH/4, 256, 0, stream>>>(hf, hb, flag, d_out);
  } else {
    k_boot<0><<<BATCH, 256, 0, stream>>>(h0, flag, dirs, nullptr, hb, coef, scl);
    for (int L = 0; L < 4; ++L) {
      gemm_tanh<<<gg, 512, 0, stream>>>(hb, W1b, b1f, scl, T);
      gemm_update<0><<<gg, 512, 0, stream>>>(T, W2b, b2f, nullptr, hb, coef, dirs);
      if (L < 3) k_stats<<<BATCH/4, 256, 0, stream>>>(hb, dirs, coef, scl);
    }
    k_finish<0><<<BATCH/4, 256, 0, stream>>>(nullptr, hb, flag, d_out);
  }
}